// Round 2
// baseline (424.250 us; speedup 1.0000x reference)
//
#include <hip/hip_runtime.h>
#include <cstdint>

// Problem constants: B=2, S=2048, D=2048, H=16, DH=128
typedef unsigned short u16;
typedef __attribute__((ext_vector_type(8))) short short8v;       // 8 x bf16 (MFMA A/B frag)
typedef __attribute__((ext_vector_type(8))) unsigned short u16x8;
typedef __attribute__((ext_vector_type(4))) float floatx4;       // MFMA C/D frag

typedef unsigned int __attribute__((address_space(1))) as1_u32;
typedef unsigned int __attribute__((address_space(3))) as3_u32;

__device__ __forceinline__ u16 f2bf(float f) {
  union { float f; unsigned u; } v; v.f = f;
  unsigned r = v.u + 0x7FFFu + ((v.u >> 16) & 1u);   // RNE, no NaN inputs here
  return (u16)(r >> 16);
}

__device__ __forceinline__ void gload16(void* lds, const void* g) {
  // async global->LDS, 16B per lane; LDS dest = wave-uniform base + lane*16
  __builtin_amdgcn_global_load_lds((as1_u32*)(uintptr_t)g, (as3_u32*)(uintptr_t)lds, 16, 0, 0);
}

// ---------------- fp32 -> bf16 conversion ----------------
__global__ __launch_bounds__(256) void f2bf_kernel(const float* __restrict__ in,
                                                   u16* __restrict__ out, int n4) {
  int i = blockIdx.x * 256 + threadIdx.x;
  const int stride = gridDim.x * 256;
  for (; i < n4; i += stride) {
    float4 v = ((const float4*)in)[i];
    ushort4 o;
    o.x = f2bf(v.x); o.y = f2bf(v.y); o.z = f2bf(v.z); o.w = f2bf(v.w);
    ((ushort4*)out)[i] = o;
  }
}

// ---------------- GEMM: C[M,N] = A[M,K] @ B[N,K]^T + bias (bf16 in, f32 acc) -------------
// m97 structure: 128x128 tile, BK=32, 4 waves (2x2), 4x4 16x16x32 MFMA frags per wave.
template <int OUT_BF16>
__global__ __launch_bounds__(256)
void gemm_bt(const u16* __restrict__ A, const u16* __restrict__ B,
             const float* __restrict__ bias, void* __restrict__ C,
             int M, int N, int K) {
  __shared__ u16 As[128 * 32];   // [row][k] 8KB
  __shared__ u16 Bs[128 * 32];   // [col][k] 8KB
  const int tid = threadIdx.x;
  const int wave = tid >> 6, lane = tid & 63;
  const int wr = wave >> 1, wc = wave & 1;
  const int li = lane & 15, lg = lane >> 4;
  const int brow = blockIdx.y * 128, bcol = blockIdx.x * 128;

  const int e0 = tid * 8, e1 = 2048 + tid * 8;
  const u16* aSrc0 = A + (size_t)(brow + (e0 >> 5)) * K + (e0 & 31);
  const u16* aSrc1 = A + (size_t)(brow + (e1 >> 5)) * K + (e1 & 31);
  const u16* bSrc0 = B + (size_t)(bcol + (e0 >> 5)) * K + (e0 & 31);
  const u16* bSrc1 = B + (size_t)(bcol + (e1 >> 5)) * K + (e1 & 31);

  floatx4 acc[4][4];
#pragma unroll
  for (int m = 0; m < 4; ++m)
#pragma unroll
    for (int n = 0; n < 4; ++n) acc[m][n] = floatx4{0.f, 0.f, 0.f, 0.f};

  for (int kt = 0; kt < K; kt += 32) {
    gload16((char*)As + tid * 16,        aSrc0 + kt);
    gload16((char*)As + 4096 + tid * 16, aSrc1 + kt);
    gload16((char*)Bs + tid * 16,        bSrc0 + kt);
    gload16((char*)Bs + 4096 + tid * 16, bSrc1 + kt);
    asm volatile("s_waitcnt vmcnt(0)" ::: "memory");
    __syncthreads();

    short8v a[4], b[4];
#pragma unroll
    for (int m = 0; m < 4; ++m)
      a[m] = *(const short8v*)&As[(wr * 64 + m * 16 + li) * 32 + lg * 8];
#pragma unroll
    for (int n = 0; n < 4; ++n)
      b[n] = *(const short8v*)&Bs[(wc * 64 + n * 16 + li) * 32 + lg * 8];
#pragma unroll
    for (int m = 0; m < 4; ++m)
#pragma unroll
      for (int n = 0; n < 4; ++n)
        acc[m][n] = __builtin_amdgcn_mfma_f32_16x16x32_bf16(a[m], b[n], acc[m][n], 0, 0, 0);
    __syncthreads();
  }

  // C/D layout: col = lane&15, row = (lane>>4)*4 + reg  (m89-verified)
  const int crow0 = brow + wr * 64 + lg * 4;
  const int ccol0 = bcol + wc * 64 + li;
#pragma unroll
  for (int n = 0; n < 4; ++n) {
    const float bv = bias[ccol0 + n * 16];
#pragma unroll
    for (int m = 0; m < 4; ++m) {
#pragma unroll
      for (int j = 0; j < 4; ++j) {
        const float v = acc[m][n][j] + bv;
        const size_t idx = (size_t)(crow0 + m * 16 + j) * N + (ccol0 + n * 16);
        if (OUT_BF16) ((u16*)C)[idx] = f2bf(v);
        else          ((float*)C)[idx] = v;
      }
    }
  }
}

// ---------------- V transpose: qkv V-part [b,s,h,dh] -> vt [b,h,dh,s] ----------------
__global__ __launch_bounds__(256)
void transpose_v(const u16* __restrict__ qkv, u16* __restrict__ vt) {
  __shared__ u16 T[64][136];   // pad to 136 (16B-aligned rows, bank-spread column reads)
  const int st = blockIdx.x, bh = blockIdx.y;
  const int b = bh >> 4, h = bh & 15;
  const int tid = threadIdx.x;
  const u16* src = qkv + (size_t)(b * 2048 + st * 64) * 6144 + 4096 + h * 128;
  u16* dst = vt + (size_t)bh * 128 * 2048 + st * 64;
#pragma unroll
  for (int p = 0; p < 4; ++p) {
    const int e = (p * 256 + tid) * 8;
    const int r = e >> 7, c = e & 127;
    *(u16x8*)&T[r][c] = *(const u16x8*)&src[(size_t)r * 6144 + c];
  }
  __syncthreads();
#pragma unroll
  for (int p = 0; p < 4; ++p) {
    const int e = (p * 256 + tid) * 8;
    const int dh = e >> 6, s0 = e & 63;
    u16x8 o;
#pragma unroll
    for (int j = 0; j < 8; ++j) o[j] = T[s0 + j][dh];
    *(u16x8*)&dst[(size_t)dh * 2048 + s0] = o;
  }
}

// ---------------- fused causal flash attention ----------------
// grid (qtile=32, b*h=32), 256 thr = 4 waves, 16 q-rows/wave, KV tile = 64.
// Bias-exact vs the reference: additive -1e9 penalties in f32 (NOT -inf skip).
// If every key in [0, qt*64] is padded, some rows in this block are
// "degenerate": all candidate keys carry exactly -1e9 (f32 rounding collapses
// s-1e9 to -1e9 since ULP(1e9)=64 > |s|) -> reference = uniform average over
// {k<=q} U {k>q non-padded}, INCLUDING future keys. Those blocks must sweep
// all 32 KV tiles with the exact additive biases; everyone else keeps the
// causal-prefix loop (skipped tiles contribute exp(-1e9)=0 exactly).
__global__ __launch_bounds__(256)
void attn_fused(const u16* __restrict__ qkv, const u16* __restrict__ vt,
                const int* __restrict__ kpm, u16* __restrict__ attn_out) {
  constexpr int S = 2048, DQ = 6144;
  __shared__ u16 Kl[64 * 128];     // 16KB
  __shared__ u16 Vl[128 * 64];     // 16KB
  __shared__ u16 Pl[4][16 * 64];   // 8KB, per-wave P tile
  __shared__ int s_any;
  const int qt = blockIdx.x, bh = blockIdx.y;
  const int b = bh >> 4, h = bh & 15;
  const int tid = threadIdx.x, wave = tid >> 6, lane = tid & 63;
  const int lg = lane >> 4, li = lane & 15;
  const int qrow0 = qt * 64 + wave * 16;

  const u16* Qb = qkv + (size_t)b * S * DQ + h * 128;
  const u16* Kb = Qb + 2048;
  const u16* Vtb = vt + (size_t)bh * 128 * 2048;
  const int* mrow = kpm + b * S;

  // does any non-padded key exist at index <= qt*64 ? (=> no degenerate rows)
  if (tid == 0) s_any = 0;
  __syncthreads();
  {
    int a = 0;
    for (int j = tid; j <= qt * 64; j += 256) a |= mrow[j];
    if (a) s_any = 1;
  }
  __syncthreads();
  const int nt = s_any ? (qt + 1) : 32;

  // Q fragments stay in registers for the whole kernel (A-frag: row=lane&15, k=(lane>>4)*8+j)
  short8v qf[4];
  {
    const u16* qp = Qb + (size_t)(qrow0 + li) * DQ + lg * 8;
#pragma unroll
    for (int kk = 0; kk < 4; ++kk) qf[kk] = *(const short8v*)(qp + kk * 32);
  }

  float mM[4], lSum[4];
  floatx4 oa[8];
#pragma unroll
  for (int j = 0; j < 4; ++j) { mM[j] = -3.0e38f; lSum[j] = 0.f; }
#pragma unroll
  for (int n = 0; n < 8; ++n) oa[n] = floatx4{0.f, 0.f, 0.f, 0.f};

  // pre-swizzled staging sources (XOR involution on bits 4-6 within a row)
  const u16* kSrc[4]; const u16* vSrc[4];
#pragma unroll
  for (int i = 0; i < 4; ++i) {
    const int L = i * 4096 + tid * 16;
    const int r = L >> 8;
    const int c = ((L & 255) ^ ((r & 7) << 4)) >> 1;
    kSrc[i] = Kb + (size_t)r * DQ + c;
    const int d = L >> 7;
    const int sv = ((L & 127) ^ ((d & 7) << 4)) >> 1;
    vSrc[i] = Vtb + (size_t)d * 2048 + sv;
  }

  const float scale = 0.08838834764831845f;  // 1/sqrt(128)
  for (int kt = 0; kt < nt; ++kt) {
    const int kv0 = kt * 64;
#pragma unroll
    for (int i = 0; i < 4; ++i) {
      gload16((char*)Kl + i * 4096 + tid * 16, kSrc[i] + (size_t)kv0 * DQ);
      gload16((char*)Vl + i * 4096 + tid * 16, vSrc[i] + kv0);
    }
    asm volatile("s_waitcnt vmcnt(0)" ::: "memory");
    __syncthreads();

    // S = Q K^T  (B-frag from swizzled K_lds)
    floatx4 sc[4];
#pragma unroll
    for (int n = 0; n < 4; ++n) {
      sc[n] = floatx4{0.f, 0.f, 0.f, 0.f};
      const int r = n * 16 + li;
#pragma unroll
      for (int kk = 0; kk < 4; ++kk) {
        const int byteo = (r * 256 + kk * 64 + lg * 16) ^ ((r & 7) << 4);
        const short8v kf = *(const short8v*)((const char*)Kl + byteo);
        sc[n] = __builtin_amdgcn_mfma_f32_16x16x32_bf16(qf[kk], kf, sc[n], 0, 0, 0);
      }
    }

    float pb[4];
#pragma unroll
    for (int n = 0; n < 4; ++n) pb[n] = (mrow[kv0 + n * 16 + li] == 0) ? -1.0e9f : 0.f;

    // online softmax; row r lives in 16-lane group lg, regs j=0..3
    float p[4][4];
#pragma unroll
    for (int j = 0; j < 4; ++j) {
      const int qg = qrow0 + lg * 4 + j;
      float t = -3.0e38f;
#pragma unroll
      for (int n = 0; n < 4; ++n) {
        float s = sc[n][j] * scale + pb[n];
        if (kv0 + n * 16 + li > qg) s -= 1.0e9f;  // causal NEG bias (additive, exact)
        p[n][j] = s;
        t = fmaxf(t, s);
      }
      t = fmaxf(t, __shfl_xor(t, 1));
      t = fmaxf(t, __shfl_xor(t, 2));
      t = fmaxf(t, __shfl_xor(t, 4));
      t = fmaxf(t, __shfl_xor(t, 8));
      const float mnew = fmaxf(mM[j], t);
      const float f = __expf(mM[j] - mnew);   // first tile: exp(-inf-ish)=0
      mM[j] = mnew;
      float rs = 0.f;
#pragma unroll
      for (int n = 0; n < 4; ++n) { const float e = __expf(p[n][j] - mnew); p[n][j] = e; rs += e; }
      rs += __shfl_xor(rs, 1);
      rs += __shfl_xor(rs, 2);
      rs += __shfl_xor(rs, 4);
      rs += __shfl_xor(rs, 8);
      lSum[j] = lSum[j] * f + rs;
#pragma unroll
      for (int n2 = 0; n2 < 8; ++n2) oa[n2][j] *= f;
    }

    // P (D-layout) -> per-wave LDS -> A-frag layout for PV
#pragma unroll
    for (int j = 0; j < 4; ++j) {
      const int q = lg * 4 + j;
#pragma unroll
      for (int n = 0; n < 4; ++n) {
        const int byteo = (q * 128 + (n * 16 + li) * 2) ^ ((q & 7) << 4);
        *(u16*)((char*)&Pl[wave][0] + byteo) = f2bf(p[n][j]);
      }
    }
    asm volatile("s_waitcnt lgkmcnt(0)" ::: "memory");

    // O += P V   (A-frag from Pl, B-frag from swizzled Vt_lds)
#pragma unroll
    for (int kk2 = 0; kk2 < 2; ++kk2) {
      const int pbyte = (li * 128 + kk2 * 64 + lg * 16) ^ ((li & 7) << 4);
      const short8v pf = *(const short8v*)((const char*)&Pl[wave][0] + pbyte);
#pragma unroll
      for (int n2 = 0; n2 < 8; ++n2) {
        const int d = n2 * 16 + li;
        const int vbyte = (d * 128 + kk2 * 64 + lg * 16) ^ ((d & 7) << 4);
        const short8v vf = *(const short8v*)((const char*)Vl + vbyte);
        oa[n2] = __builtin_amdgcn_mfma_f32_16x16x32_bf16(pf, vf, oa[n2], 0, 0, 0);
      }
    }
    __syncthreads();   // protect Kl/Vl before next tile's staging
  }

  // epilogue: attn[b,s,h,dh] bf16, rows fully covered
#pragma unroll
  for (int j = 0; j < 4; ++j) {
    const float inv = 1.0f / lSum[j];
    const size_t row = (size_t)b * S + qrow0 + lg * 4 + j;
#pragma unroll
    for (int n2 = 0; n2 < 8; ++n2) {
      attn_out[row * 2048 + h * 128 + n2 * 16 + li] = f2bf(oa[n2][j] * inv);
    }
  }
}

// ---------------- launch ----------------
extern "C" void kernel_launch(void* const* d_in, const int* in_sizes, int n_in,
                              void* d_out, int out_size, void* d_ws, size_t ws_size,
                              hipStream_t stream) {
  const float* x    = (const float*)d_in[0];   // [2,2048,2048]
  const int*   kpm  = (const int*)d_in[1];     // [2,2048]
  const float* wqkv = (const float*)d_in[2];   // [6144,2048]
  const float* bqkv = (const float*)d_in[3];   // [6144]
  const float* wout = (const float*)d_in[4];   // [2048,2048]
  const float* bout = (const float*)d_in[5];   // [2048]
  float* out = (float*)d_out;

  char* ws = (char*)d_ws;
  u16* xbf   = (u16*)(ws);                    // 16 MiB: x bf16 [4096,2048]
  u16* wqbf  = (u16*)(ws + (16u << 20));      // 24 MiB: Wqkv bf16 [6144,2048]
  u16* wobf  = (u16*)(ws + (40u << 20));      //  8 MiB: out_w bf16 [2048,2048]
  u16* qkvb  = (u16*)(ws + (48u << 20));      // 48 MiB: qkv bf16 [4096,6144]
  u16* vtb   = (u16*)(ws + (96u << 20));      // 16 MiB: V^T bf16 [32,128,2048]
  u16* attnb = (u16*)(ws + (112u << 20));     // 16 MiB: attn bf16 [4096,2048]

  f2bf_kernel<<<1024, 256, 0, stream>>>(x,    xbf,  4096 * 2048 / 4);
  f2bf_kernel<<<1024, 256, 0, stream>>>(wqkv, wqbf, 6144 * 2048 / 4);
  f2bf_kernel<<<1024, 256, 0, stream>>>(wout, wobf, 2048 * 2048 / 4);

  gemm_bt<1><<<dim3(48, 32), 256, 0, stream>>>(xbf, wqbf, bqkv, qkvb, 4096, 6144, 2048);
  transpose_v<<<dim3(32, 32), 256, 0, stream>>>(qkvb, vtb);
  attn_fused<<<dim3(32, 32), 256, 0, stream>>>(qkvb, vtb, kpm, attnb);
  gemm_bt<0><<<dim3(16, 32), 256, 0, stream>>>(attnb, wobf, bout, out, 4096, 2048, 2048);
}

// Round 3
// 419.344 us; speedup vs baseline: 1.0117x; 1.0117x over previous
//
#include <hip/hip_runtime.h>
#include <cstdint>

// Problem constants: B=2, S=2048, D=2048, H=16, DH=128
typedef unsigned short u16;
typedef __attribute__((ext_vector_type(8))) short short8v;       // 8 x bf16 (MFMA A/B frag)
typedef __attribute__((ext_vector_type(8))) unsigned short u16x8;
typedef __attribute__((ext_vector_type(4))) float floatx4;       // MFMA C/D frag

typedef unsigned int __attribute__((address_space(1))) as1_u32;
typedef unsigned int __attribute__((address_space(3))) as3_u32;

__device__ __forceinline__ u16 f2bf(float f) {
  union { float f; unsigned u; } v; v.f = f;
  unsigned r = v.u + 0x7FFFu + ((v.u >> 16) & 1u);   // RNE, no NaN inputs here
  return (u16)(r >> 16);
}

__device__ __forceinline__ void gload16(void* lds, const void* g) {
  // async global->LDS, 16B per lane; LDS dest = wave-uniform base + lane*16
  __builtin_amdgcn_global_load_lds((as1_u32*)(uintptr_t)g, (as3_u32*)(uintptr_t)lds, 16, 0, 0);
}

// ---------------- fp32 -> bf16 conversion ----------------
__global__ __launch_bounds__(256) void f2bf_kernel(const float* __restrict__ in,
                                                   u16* __restrict__ out, int n4) {
  int i = blockIdx.x * 256 + threadIdx.x;
  const int stride = gridDim.x * 256;
  for (; i < n4; i += stride) {
    float4 v = ((const float4*)in)[i];
    ushort4 o;
    o.x = f2bf(v.x); o.y = f2bf(v.y); o.z = f2bf(v.z); o.w = f2bf(v.w);
    ((ushort4*)out)[i] = o;
  }
}

// ---------------- GEMM: C[M,N] = A[M,K] @ B[N,K]^T + bias (bf16 in, f32 acc) -------------
template <int OUT_BF16>
__global__ __launch_bounds__(256)
void gemm_bt(const u16* __restrict__ A, const u16* __restrict__ B,
             const float* __restrict__ bias, void* __restrict__ C,
             int M, int N, int K) {
  __shared__ u16 As[128 * 32];   // [row][k] 8KB
  __shared__ u16 Bs[128 * 32];   // [col][k] 8KB
  const int tid = threadIdx.x;
  const int wave = tid >> 6, lane = tid & 63;
  const int wr = wave >> 1, wc = wave & 1;
  const int li = lane & 15, lg = lane >> 4;
  const int brow = blockIdx.y * 128, bcol = blockIdx.x * 128;

  const int e0 = tid * 8, e1 = 2048 + tid * 8;
  const u16* aSrc0 = A + (size_t)(brow + (e0 >> 5)) * K + (e0 & 31);
  const u16* aSrc1 = A + (size_t)(brow + (e1 >> 5)) * K + (e1 & 31);
  const u16* bSrc0 = B + (size_t)(bcol + (e0 >> 5)) * K + (e0 & 31);
  const u16* bSrc1 = B + (size_t)(bcol + (e1 >> 5)) * K + (e1 & 31);

  floatx4 acc[4][4];
#pragma unroll
  for (int m = 0; m < 4; ++m)
#pragma unroll
    for (int n = 0; n < 4; ++n) acc[m][n] = floatx4{0.f, 0.f, 0.f, 0.f};

  for (int kt = 0; kt < K; kt += 32) {
    gload16((char*)As + tid * 16,        aSrc0 + kt);
    gload16((char*)As + 4096 + tid * 16, aSrc1 + kt);
    gload16((char*)Bs + tid * 16,        bSrc0 + kt);
    gload16((char*)Bs + 4096 + tid * 16, bSrc1 + kt);
    asm volatile("s_waitcnt vmcnt(0)" ::: "memory");
    __syncthreads();

    short8v a[4], b[4];
#pragma unroll
    for (int m = 0; m < 4; ++m)
      a[m] = *(const short8v*)&As[(wr * 64 + m * 16 + li) * 32 + lg * 8];
#pragma unroll
    for (int n = 0; n < 4; ++n)
      b[n] = *(const short8v*)&Bs[(wc * 64 + n * 16 + li) * 32 + lg * 8];
#pragma unroll
    for (int m = 0; m < 4; ++m)
#pragma unroll
      for (int n = 0; n < 4; ++n)
        acc[m][n] = __builtin_amdgcn_mfma_f32_16x16x32_bf16(a[m], b[n], acc[m][n], 0, 0, 0);
    __syncthreads();
  }

  const int crow0 = brow + wr * 64 + lg * 4;
  const int ccol0 = bcol + wc * 64 + li;
#pragma unroll
  for (int n = 0; n < 4; ++n) {
    const float bv = bias[ccol0 + n * 16];
#pragma unroll
    for (int m = 0; m < 4; ++m) {
#pragma unroll
      for (int j = 0; j < 4; ++j) {
        const float v = acc[m][n][j] + bv;
        const size_t idx = (size_t)(crow0 + m * 16 + j) * N + (ccol0 + n * 16);
        if (OUT_BF16) ((u16*)C)[idx] = f2bf(v);
        else          ((float*)C)[idx] = v;
      }
    }
  }
}

// ---------------- V transpose: qkv V-part [b,s,h,dh] -> vt [b,h,dh,s] ----------------
__global__ __launch_bounds__(256)
void transpose_v(const u16* __restrict__ qkv, u16* __restrict__ vt) {
  __shared__ u16 T[64][136];
  const int st = blockIdx.x, bh = blockIdx.y;
  const int b = bh >> 4, h = bh & 15;
  const int tid = threadIdx.x;
  const u16* src = qkv + (size_t)(b * 2048 + st * 64) * 6144 + 4096 + h * 128;
  u16* dst = vt + (size_t)bh * 128 * 2048 + st * 64;
#pragma unroll
  for (int p = 0; p < 4; ++p) {
    const int e = (p * 256 + tid) * 8;
    const int r = e >> 7, c = e & 127;
    *(u16x8*)&T[r][c] = *(const u16x8*)&src[(size_t)r * 6144 + c];
  }
  __syncthreads();
#pragma unroll
  for (int p = 0; p < 4; ++p) {
    const int e = (p * 256 + tid) * 8;
    const int dh = e >> 6, s0 = e & 63;
    u16x8 o;
#pragma unroll
    for (int j = 0; j < 8; ++j) o[j] = T[s0 + j][dh];
    *(u16x8*)&dst[(size_t)dh * 2048 + s0] = o;
  }
}

// ---------------- fused causal flash attention (pipelined) ----------------
// grid (qtile, b*h), 256 thr = 4 waves, 16 q-rows/wave, KV tile = 64.
// K double-buffered, V single-buffered staged late (covered by QK^T+softmax of
// the next iter). Raw s_barrier + counted vmcnt (never 0 mid-loop).
// Per-wave VMEM FIFO (4 loads per stage-call):
//   prologue: K0,V0 (8 out)
//   iter t:  issue K(t+1) (12 out) -> vmcnt(4) drains K(t),V(t), keeps K(t+1)
//            barrier; QK^T+softmax+PV; barrier; issue V(t+1) (8 out)
// Bias-exact vs reference: additive -1e9 penalties in f32. Degenerate blocks
// (no valid key <= qt*64) sweep all 32 KV tiles with exact biases.
__global__ __launch_bounds__(256)
void attn_fused(const u16* __restrict__ qkv, const u16* __restrict__ vt,
                const int* __restrict__ kpm, u16* __restrict__ attn_out) {
  constexpr int S = 2048, DQ = 6144;
  __shared__ u16 Kl[2][64 * 128];  // 32KB (double-buffered)
  __shared__ u16 Vl[128 * 64];     // 16KB (single)
  __shared__ u16 Pl[4][16 * 64];   // 8KB, per-wave P tile
  __shared__ u16 msk[2048];        // 4KB key-padding flags
  __shared__ int s_any;
  const int qt = 31 - (int)blockIdx.x;   // LPT: longest blocks first
  const int bh = blockIdx.y;
  const int b = bh >> 4, h = bh & 15;
  const int tid = threadIdx.x, wave = tid >> 6, lane = tid & 63;
  const int lg = lane >> 4, li = lane & 15;
  const int qrow0 = qt * 64 + wave * 16;

  const u16* Qb = qkv + (size_t)b * S * DQ + h * 128;
  const u16* Kb = Qb + 2048;
  const u16* Vtb = vt + (size_t)bh * 128 * 2048;
  const int* mrow = kpm + b * S;

  if (tid == 0) s_any = 0;
  __syncthreads();
  {
    int a = 0;
    for (int j = tid; j < 2048; j += 256) {
      const int m = mrow[j];
      msk[j] = (u16)(m != 0);
      if (m && j <= qt * 64) a = 1;
    }
    if (a) s_any = 1;
  }
  __syncthreads();
  const int anyv = s_any;
  const int nt = anyv ? (qt + 1) : 32;
  const int causalFrom = anyv ? qt : 0;

  // Q fragments in registers (A-frag: row=lane&15, k=(lane>>4)*8+j)
  short8v qf[4];
  {
    const u16* qp = Qb + (size_t)(qrow0 + li) * DQ + lg * 8;
#pragma unroll
    for (int kk = 0; kk < 4; ++kk) qf[kk] = *(const short8v*)(qp + kk * 32);
  }

  float mM[4], lSum[4];
  floatx4 oa[8];
#pragma unroll
  for (int j = 0; j < 4; ++j) { mM[j] = -3.0e38f; lSum[j] = 0.f; }
#pragma unroll
  for (int n = 0; n < 8; ++n) oa[n] = floatx4{0.f, 0.f, 0.f, 0.f};

  // pre-swizzled staging sources (XOR involution on bits 4-6 within a row)
  const u16* kSrc[4]; const u16* vSrc[4];
#pragma unroll
  for (int i = 0; i < 4; ++i) {
    const int L = i * 4096 + tid * 16;
    const int r = L >> 8;
    const int c = ((L & 255) ^ ((r & 7) << 4)) >> 1;
    kSrc[i] = Kb + (size_t)r * DQ + c;
    const int d = L >> 7;
    const int sv = ((L & 127) ^ ((d & 7) << 4)) >> 1;
    vSrc[i] = Vtb + (size_t)d * 2048 + sv;
  }

#define STAGE_K(buf, kt_)                                                      \
  {                                                                            \
    const int kv0_ = (kt_) * 64;                                               \
    _Pragma("unroll")                                                          \
    for (int i = 0; i < 4; ++i)                                                \
      gload16((char*)Kl + (buf) * 16384 + i * 4096 + tid * 16,                 \
              kSrc[i] + (size_t)kv0_ * DQ);                                    \
  }
#define STAGE_V(kt_)                                                           \
  {                                                                            \
    const int kv0_ = (kt_) * 64;                                               \
    _Pragma("unroll")                                                          \
    for (int i = 0; i < 4; ++i)                                                \
      gload16((char*)Vl + i * 4096 + tid * 16, vSrc[i] + kv0_);                \
  }

  const float scale = 0.08838834764831845f;  // 1/sqrt(128)

  STAGE_K(0, 0);
  STAGE_V(0);

  for (int kt = 0; kt < nt; ++kt) {
    const int cur = kt & 1;
    const int kv0 = kt * 64;
    if (kt + 1 < nt) {
      STAGE_K(cur ^ 1, kt + 1);
      asm volatile("s_waitcnt vmcnt(4)" ::: "memory");
    } else {
      asm volatile("s_waitcnt vmcnt(0)" ::: "memory");
    }
    __builtin_amdgcn_s_barrier();

    const char* Kcur = (const char*)Kl + cur * 16384;

    // S = Q K^T  (B-frag from swizzled K_lds)
    floatx4 sc[4];
#pragma unroll
    for (int n = 0; n < 4; ++n) {
      sc[n] = floatx4{0.f, 0.f, 0.f, 0.f};
      const int r = n * 16 + li;
#pragma unroll
      for (int kk = 0; kk < 4; ++kk) {
        const int byteo = (r * 256 + kk * 64 + lg * 16) ^ ((r & 7) << 4);
        const short8v kf = *(const short8v*)(Kcur + byteo);
        sc[n] = __builtin_amdgcn_mfma_f32_16x16x32_bf16(qf[kk], kf, sc[n], 0, 0, 0);
      }
    }

    float pb[4];
#pragma unroll
    for (int n = 0; n < 4; ++n) pb[n] = msk[kv0 + n * 16 + li] ? 0.f : -1.0e9f;
    const bool cz = (kt >= causalFrom);

    // online softmax; row r lives in 16-lane group lg, regs j=0..3
    float p[4][4];
#pragma unroll
    for (int j = 0; j < 4; ++j) {
      const int qg = qrow0 + lg * 4 + j;
      float t = -3.0e38f;
#pragma unroll
      for (int n = 0; n < 4; ++n) {
        float s = sc[n][j] * scale + pb[n];
        if (cz && (kv0 + n * 16 + li > qg)) s -= 1.0e9f;  // causal NEG (additive)
        p[n][j] = s;
        t = fmaxf(t, s);
      }
      t = fmaxf(t, __shfl_xor(t, 1));
      t = fmaxf(t, __shfl_xor(t, 2));
      t = fmaxf(t, __shfl_xor(t, 4));
      t = fmaxf(t, __shfl_xor(t, 8));
      const float mnew = fmaxf(mM[j], t);
      const float f = __expf(mM[j] - mnew);
      mM[j] = mnew;
      float rs = 0.f;
#pragma unroll
      for (int n = 0; n < 4; ++n) { const float e = __expf(p[n][j] - mnew); p[n][j] = e; rs += e; }
      rs += __shfl_xor(rs, 1);
      rs += __shfl_xor(rs, 2);
      rs += __shfl_xor(rs, 4);
      rs += __shfl_xor(rs, 8);
      lSum[j] = lSum[j] * f + rs;
#pragma unroll
      for (int n2 = 0; n2 < 8; ++n2) oa[n2][j] *= f;
    }

    // P (D-layout) -> per-wave LDS -> A-frag layout for PV
#pragma unroll
    for (int j = 0; j < 4; ++j) {
      const int q = lg * 4 + j;
#pragma unroll
      for (int n = 0; n < 4; ++n) {
        const int byteo = (q * 128 + (n * 16 + li) * 2) ^ ((q & 7) << 4);
        *(u16*)((char*)&Pl[wave][0] + byteo) = f2bf(p[n][j]);
      }
    }
    asm volatile("s_waitcnt lgkmcnt(0)" ::: "memory");

    // O += P V   (A-frag from Pl, B-frag from swizzled Vt_lds)
#pragma unroll
    for (int kk2 = 0; kk2 < 2; ++kk2) {
      const int pbyte = (li * 128 + kk2 * 64 + lg * 16) ^ ((li & 7) << 4);
      const short8v pf = *(const short8v*)((const char*)&Pl[wave][0] + pbyte);
#pragma unroll
      for (int n2 = 0; n2 < 8; ++n2) {
        const int d = n2 * 16 + li;
        const int vbyte = (d * 128 + kk2 * 64 + lg * 16) ^ ((d & 7) << 4);
        const short8v vf = *(const short8v*)((const char*)Vl + vbyte);
        oa[n2] = __builtin_amdgcn_mfma_f32_16x16x32_bf16(pf, vf, oa[n2], 0, 0, 0);
      }
    }
    __builtin_amdgcn_s_barrier();   // all reads of Kl[cur^1]-next-target & Vl done
    if (kt + 1 < nt) STAGE_V(kt + 1);
  }

  // epilogue
#pragma unroll
  for (int j = 0; j < 4; ++j) {
    const float inv = 1.0f / lSum[j];
    const size_t row = (size_t)b * S + qrow0 + lg * 4 + j;
#pragma unroll
    for (int n2 = 0; n2 < 8; ++n2) {
      attn_out[row * 2048 + h * 128 + n2 * 16 + li] = f2bf(oa[n2][j] * inv);
    }
  }
#undef STAGE_K
#undef STAGE_V
}

// ---------------- launch ----------------
extern "C" void kernel_launch(void* const* d_in, const int* in_sizes, int n_in,
                              void* d_out, int out_size, void* d_ws, size_t ws_size,
                              hipStream_t stream) {
  const float* x    = (const float*)d_in[0];   // [2,2048,2048]
  const int*   kpm  = (const int*)d_in[1];     // [2,2048]
  const float* wqkv = (const float*)d_in[2];   // [6144,2048]
  const float* bqkv = (const float*)d_in[3];   // [6144]
  const float* wout = (const float*)d_in[4];   // [2048,2048]
  const float* bout = (const float*)d_in[5];   // [2048]
  float* out = (float*)d_out;

  char* ws = (char*)d_ws;
  u16* xbf   = (u16*)(ws);                    // 16 MiB: x bf16 [4096,2048]
  u16* wqbf  = (u16*)(ws + (16u << 20));      // 24 MiB: Wqkv bf16 [6144,2048]
  u16* wobf  = (u16*)(ws + (40u << 20));      //  8 MiB: out_w bf16 [2048,2048]
  u16* qkvb  = (u16*)(ws + (48u << 20));      // 48 MiB: qkv bf16 [4096,6144]
  u16* vtb   = (u16*)(ws + (96u << 20));      // 16 MiB: V^T bf16 [32,128,2048]
  u16* attnb = (u16*)(ws + (112u << 20));     // 16 MiB: attn bf16 [4096,2048]

  f2bf_kernel<<<1024, 256, 0, stream>>>(x,    xbf,  4096 * 2048 / 4);
  f2bf_kernel<<<1024, 256, 0, stream>>>(wqkv, wqbf, 6144 * 2048 / 4);
  f2bf_kernel<<<1024, 256, 0, stream>>>(wout, wobf, 2048 * 2048 / 4);

  gemm_bt<1><<<dim3(48, 32), 256, 0, stream>>>(xbf, wqbf, bqkv, qkvb, 4096, 6144, 2048);
  transpose_v<<<dim3(32, 32), 256, 0, stream>>>(qkvb, vtb);
  attn_fused<<<dim3(32, 32), 256, 0, stream>>>(qkvb, vtb, kpm, attnb);
  gemm_bt<0><<<dim3(16, 32), 256, 0, stream>>>(attnb, wobf, bout, out, 4096, 2048, 2048);
}

// Round 4
// 341.733 us; speedup vs baseline: 1.2415x; 1.2271x over previous
//
#include <hip/hip_runtime.h>
#include <cstdint>

// Problem constants: B=2, S=2048, D=2048, H=16, DH=128
typedef unsigned short u16;
typedef __attribute__((ext_vector_type(8))) short short8v;       // 8 x bf16 (MFMA A/B frag)
typedef __attribute__((ext_vector_type(8))) unsigned short u16x8;
typedef __attribute__((ext_vector_type(4))) float floatx4;       // MFMA C/D frag

typedef unsigned int __attribute__((address_space(1))) as1_u32;
typedef unsigned int __attribute__((address_space(3))) as3_u32;

__device__ __forceinline__ u16 f2bf(float f) {
  union { float f; unsigned u; } v; v.f = f;
  unsigned r = v.u + 0x7FFFu + ((v.u >> 16) & 1u);   // RNE
  return (u16)(r >> 16);
}

__device__ __forceinline__ unsigned cvt_pk_bf16(float lo, float hi) {
  unsigned r;
  asm("v_cvt_pk_bf16_f32 %0, %1, %2" : "=v"(r) : "v"(lo), "v"(hi));
  return r;
}

__device__ __forceinline__ void gload16(void* lds, const void* g) {
  __builtin_amdgcn_global_load_lds((as1_u32*)(uintptr_t)g, (as3_u32*)(uintptr_t)lds, 16, 0, 0);
}

// ---------------- fp32 -> bf16 conversion ----------------
__global__ __launch_bounds__(256) void f2bf_kernel(const float* __restrict__ in,
                                                   u16* __restrict__ out, int n4) {
  int i = blockIdx.x * 256 + threadIdx.x;
  const int stride = gridDim.x * 256;
  for (; i < n4; i += stride) {
    float4 v = ((const float4*)in)[i];
    ushort4 o;
    o.x = f2bf(v.x); o.y = f2bf(v.y); o.z = f2bf(v.z); o.w = f2bf(v.w);
    ((ushort4*)out)[i] = o;
  }
}

// ---------------- GEMM: C[M,N] = A[M,K] @ B[N,K]^T + bias ----------------
template <int OUT_BF16>
__global__ __launch_bounds__(256)
void gemm_bt(const u16* __restrict__ A, const u16* __restrict__ B,
             const float* __restrict__ bias, void* __restrict__ C,
             int M, int N, int K) {
  __shared__ u16 As[128 * 32];
  __shared__ u16 Bs[128 * 32];
  const int tid = threadIdx.x;
  const int wave = tid >> 6, lane = tid & 63;
  const int wr = wave >> 1, wc = wave & 1;
  const int li = lane & 15, lg = lane >> 4;
  const int brow = blockIdx.y * 128, bcol = blockIdx.x * 128;

  const int e0 = tid * 8, e1 = 2048 + tid * 8;
  const u16* aSrc0 = A + (size_t)(brow + (e0 >> 5)) * K + (e0 & 31);
  const u16* aSrc1 = A + (size_t)(brow + (e1 >> 5)) * K + (e1 & 31);
  const u16* bSrc0 = B + (size_t)(bcol + (e0 >> 5)) * K + (e0 & 31);
  const u16* bSrc1 = B + (size_t)(bcol + (e1 >> 5)) * K + (e1 & 31);

  floatx4 acc[4][4];
#pragma unroll
  for (int m = 0; m < 4; ++m)
#pragma unroll
    for (int n = 0; n < 4; ++n) acc[m][n] = floatx4{0.f, 0.f, 0.f, 0.f};

  for (int kt = 0; kt < K; kt += 32) {
    gload16((char*)As + tid * 16,        aSrc0 + kt);
    gload16((char*)As + 4096 + tid * 16, aSrc1 + kt);
    gload16((char*)Bs + tid * 16,        bSrc0 + kt);
    gload16((char*)Bs + 4096 + tid * 16, bSrc1 + kt);
    asm volatile("s_waitcnt vmcnt(0)" ::: "memory");
    __syncthreads();

    short8v a[4], b[4];
#pragma unroll
    for (int m = 0; m < 4; ++m)
      a[m] = *(const short8v*)&As[(wr * 64 + m * 16 + li) * 32 + lg * 8];
#pragma unroll
    for (int n = 0; n < 4; ++n)
      b[n] = *(const short8v*)&Bs[(wc * 64 + n * 16 + li) * 32 + lg * 8];
#pragma unroll
    for (int m = 0; m < 4; ++m)
#pragma unroll
      for (int n = 0; n < 4; ++n)
        acc[m][n] = __builtin_amdgcn_mfma_f32_16x16x32_bf16(a[m], b[n], acc[m][n], 0, 0, 0);
    __syncthreads();
  }

  const int crow0 = brow + wr * 64 + lg * 4;
  const int ccol0 = bcol + wc * 64 + li;
#pragma unroll
  for (int n = 0; n < 4; ++n) {
    const float bv = bias[ccol0 + n * 16];
#pragma unroll
    for (int m = 0; m < 4; ++m) {
#pragma unroll
      for (int j = 0; j < 4; ++j) {
        const float v = acc[m][n][j] + bv;
        const size_t idx = (size_t)(crow0 + m * 16 + j) * N + (ccol0 + n * 16);
        if (OUT_BF16) ((u16*)C)[idx] = f2bf(v);
        else          ((float*)C)[idx] = v;
      }
    }
  }
}

// ---------------- V transpose: qkv V-part [b,s,h,dh] -> vt [b,h,dh,s] ----------------
__global__ __launch_bounds__(256)
void transpose_v(const u16* __restrict__ qkv, u16* __restrict__ vt) {
  __shared__ u16 T[64][136];
  const int st = blockIdx.x, bh = blockIdx.y;
  const int b = bh >> 4, h = bh & 15;
  const int tid = threadIdx.x;
  const u16* src = qkv + (size_t)(b * 2048 + st * 64) * 6144 + 4096 + h * 128;
  u16* dst = vt + (size_t)bh * 128 * 2048 + st * 64;
#pragma unroll
  for (int p = 0; p < 4; ++p) {
    const int e = (p * 256 + tid) * 8;
    const int r = e >> 7, c = e & 127;
    *(u16x8*)&T[r][c] = *(const u16x8*)&src[(size_t)r * 6144 + c];
  }
  __syncthreads();
#pragma unroll
  for (int p = 0; p < 4; ++p) {
    const int e = (p * 256 + tid) * 8;
    const int dh = e >> 6, s0 = e & 63;
    u16x8 o;
#pragma unroll
    for (int j = 0; j < 8; ++j) o[j] = T[s0 + j][dh];
    *(u16x8*)&dst[(size_t)dh * 2048 + s0] = o;
  }
}

// ---------------- fused causal flash attention (swapped-operand, reg softmax) -------
// grid (16, 32): 128 q-rows/block, 4 waves x 32 rows. KV tile 64.
// Swapped QK^T: sc = mfma(A=K, B=Q) -> lane holds q-rows {li,16+li}, 16 scores
// in-register per row -> softmax is in-lane + 2 shuffles. P goes to PV's B-frag
// via cvt_pk_bf16 + permlane32/16_swap (no LDS round trip).
// PV: O^T = mfma(A=V^T, B=P).
// Ledger (per wave, 4 loads/stage): top vmcnt(8) drains K(t) (keeps V(t),K(t+1));
// mid vmcnt(4) drains V(t) (keeps K(t+1)); V(t+1) staged after barrier3.
__global__ __launch_bounds__(256, 2)
void attn_fused(const u16* __restrict__ qkv, const u16* __restrict__ vt,
                const int* __restrict__ kpm, u16* __restrict__ attn_out) {
  constexpr int S = 2048, DQ = 6144;
  __shared__ u16 Kl[2][64 * 128];   // 32KB, double-buffered; reused as O-staging
  __shared__ u16 Vl[128 * 64];      // 16KB
  __shared__ float mskf[2048];      // 8KB additive pad penalties
  __shared__ int s_any;
  const int bx = blockIdx.x, by = blockIdx.y;
  // pairing balance: co-resident pair {id, id+256} differs in by by 16 -> qt sums to 15
  const int qt = ((by >> 4) & 1) ? bx : (15 - bx);
  const int bh = by;
  const int b = bh >> 4, h = bh & 15;
  const int tid = threadIdx.x, wave = tid >> 6, lane = tid & 63;
  const int lg = lane >> 4, li = lane & 15;
  const int qrow0 = qt * 128 + wave * 32;

  const u16* Qb = qkv + (size_t)b * S * DQ + h * 128;
  const u16* Kb = Qb + 2048;
  const u16* Vtb = vt + (size_t)bh * 128 * 2048;
  const int* mrow = kpm + b * S;

  if (tid == 0) s_any = 0;
  __syncthreads();
  {
    int a = 0;
    for (int j = tid; j < 2048; j += 256) {
      const int mv = mrow[j];
      mskf[j] = mv ? 0.f : -1.0e9f;
      if (mv && j <= qt * 128) a = 1;
    }
    if (a) s_any = 1;
  }
  __syncthreads();
  const int anyv = s_any;
  const int nt = anyv ? (2 * qt + 2) : 32;
  const int causalFromW = anyv ? (qrow0 >> 6) : 0;

  // Q as B-fragments: qb[m][kk] -> col=li is q-row qrow0+m*16+li, k=kk*32+lg*8+{0..7}
  short8v qb[2][4];
#pragma unroll
  for (int m = 0; m < 2; ++m) {
    const u16* qp = Qb + (size_t)(qrow0 + m * 16 + li) * DQ + lg * 8;
#pragma unroll
    for (int kk = 0; kk < 4; ++kk) qb[m][kk] = *(const short8v*)(qp + kk * 32);
  }
  asm volatile("s_waitcnt vmcnt(0)" ::: "memory");  // clean VMEM ledger

  float mM[2], lSum[2];
  floatx4 oa[2][8];
#pragma unroll
  for (int m = 0; m < 2; ++m) {
    mM[m] = -3.0e38f; lSum[m] = 0.f;
#pragma unroll
    for (int n = 0; n < 8; ++n) oa[m][n] = floatx4{0.f, 0.f, 0.f, 0.f};
  }

  // pre-swizzled staging sources (XOR involution on bits 4-6 within a row)
  const u16* kSrc[4]; const u16* vSrc[4];
#pragma unroll
  for (int i = 0; i < 4; ++i) {
    const int L = i * 4096 + tid * 16;
    const int r = L >> 8;
    const int c = ((L & 255) ^ ((r & 7) << 4)) >> 1;
    kSrc[i] = Kb + (size_t)r * DQ + c;
    const int d = L >> 7;
    const int sv = ((L & 127) ^ ((d & 7) << 4)) >> 1;
    vSrc[i] = Vtb + (size_t)d * 2048 + sv;
  }

#define STAGE_K(buf, kt_)                                                      \
  {                                                                            \
    const int kv0_ = (kt_) * 64;                                               \
    _Pragma("unroll")                                                          \
    for (int i = 0; i < 4; ++i)                                                \
      gload16((char*)Kl + (buf) * 16384 + i * 4096 + tid * 16,                 \
              kSrc[i] + (size_t)kv0_ * DQ);                                    \
  }
#define STAGE_V(kt_)                                                           \
  {                                                                            \
    const int kv0_ = (kt_) * 64;                                               \
    _Pragma("unroll")                                                          \
    for (int i = 0; i < 4; ++i)                                                \
      gload16((char*)Vl + i * 4096 + tid * 16, vSrc[i] + kv0_);                \
  }

  const float scale = 0.08838834764831845f;  // 1/sqrt(128)

  STAGE_K(0, 0);
  STAGE_V(0);

  for (int kt = 0; kt < nt; ++kt) {
    const int cur = kt & 1;
    const int kv0 = kt * 64;
    if (kt + 1 < nt) {
      STAGE_K(cur ^ 1, kt + 1);
      asm volatile("s_waitcnt vmcnt(8)" ::: "memory");  // K(t) landed
    } else {
      asm volatile("s_waitcnt vmcnt(4)" ::: "memory");
    }
    __builtin_amdgcn_s_barrier();

    const char* Kcur = (const char*)Kl + cur * 16384;

    // S^T = K Q^T : sc[m][n] lane holds q=qrow0+m*16+li, keys kv0+n*16+lg*4+j
    floatx4 sc[2][4];
#pragma unroll
    for (int n = 0; n < 4; ++n) { sc[0][n] = floatx4{0,0,0,0}; sc[1][n] = floatx4{0,0,0,0}; }
#pragma unroll
    for (int n = 0; n < 4; ++n) {
      const int r = n * 16 + li;
#pragma unroll
      for (int kk = 0; kk < 4; ++kk) {
        const int byteo = (r * 256 + kk * 64 + lg * 16) ^ ((r & 7) << 4);
        const short8v kf = *(const short8v*)(Kcur + byteo);
        sc[0][n] = __builtin_amdgcn_mfma_f32_16x16x32_bf16(kf, qb[0][kk], sc[0][n], 0, 0, 0);
        sc[1][n] = __builtin_amdgcn_mfma_f32_16x16x32_bf16(kf, qb[1][kk], sc[1][n], 0, 0, 0);
      }
    }

    floatx4 pbv[4];
#pragma unroll
    for (int n = 0; n < 4; ++n)
      pbv[n] = *(const floatx4*)&mskf[kv0 + n * 16 + lg * 4];
    const bool cz = (kt >= causalFromW);

    short8v pf[2][2];   // [m][kk2] PV B-frags
#pragma unroll
    for (int m = 0; m < 2; ++m) {
      const int q_l = qrow0 + m * 16 + li;
      float tmax = -3.0e38f;
#pragma unroll
      for (int n = 0; n < 4; ++n)
#pragma unroll
        for (int j = 0; j < 4; ++j) {
          float s = sc[m][n][j] * scale + pbv[n][j];
          if (cz && (kv0 + n * 16 + lg * 4 + j > q_l)) s -= 1.0e9f;
          sc[m][n][j] = s;
          tmax = fmaxf(tmax, s);
        }
      tmax = fmaxf(tmax, __shfl_xor(tmax, 16));
      tmax = fmaxf(tmax, __shfl_xor(tmax, 32));
      const float mnew = fmaxf(mM[m], tmax);
      const float f = __expf(mM[m] - mnew);
      mM[m] = mnew;
      float rs = 0.f;
#pragma unroll
      for (int n = 0; n < 4; ++n)
#pragma unroll
        for (int j = 0; j < 4; ++j) {
          const float e = __expf(sc[m][n][j] - mnew);
          sc[m][n][j] = e; rs += e;
        }
      rs += __shfl_xor(rs, 16);
      rs += __shfl_xor(rs, 32);
      lSum[m] = lSum[m] * f + rs;
#pragma unroll
      for (int n2 = 0; n2 < 8; ++n2) oa[m][n2] *= f;

      // pack P to bf16 and redistribute into B-frag layout:
      // value w32[n][h] (keys n*16+lg*4+{2h,2h+1}) -> target group g=2(n&1)+(lg>>1),
      // slot (kk2=n>>1, w=2(lg&1)+h). {T[w=h],T[w=2+h]} = p16swap(p32swap(w32[2kk2][h], w32[2kk2+1][h]))
      unsigned w32[4][2];
#pragma unroll
      for (int n = 0; n < 4; ++n) {
        w32[n][0] = cvt_pk_bf16(sc[m][n][0], sc[m][n][1]);
        w32[n][1] = cvt_pk_bf16(sc[m][n][2], sc[m][n][3]);
      }
      union PF { short8v s; unsigned w[4]; } pfu[2];
#pragma unroll
      for (int kk2 = 0; kk2 < 2; ++kk2) {
#pragma unroll
        for (int hh = 0; hh < 2; ++hh) {
          unsigned u = w32[2 * kk2][hh], v = w32[2 * kk2 + 1][hh];
          asm volatile("v_permlane32_swap_b32 %0, %1" : "+v"(u), "+v"(v));
          asm volatile("v_permlane16_swap_b32 %0, %1" : "+v"(u), "+v"(v));
          pfu[kk2].w[hh] = u;
          pfu[kk2].w[2 + hh] = v;
        }
      }
      pf[m][0] = pfu[0].s;
      pf[m][1] = pfu[1].s;
    }

    if (kt + 1 < nt) asm volatile("s_waitcnt vmcnt(4)" ::: "memory");  // V(t) landed
    else             asm volatile("s_waitcnt vmcnt(0)" ::: "memory");
    __builtin_amdgcn_s_barrier();

    // O^T += V^T P^T : A-frag row=li -> d=n2*16+li, k=keys
#pragma unroll
    for (int kk2 = 0; kk2 < 2; ++kk2) {
#pragma unroll
      for (int n2 = 0; n2 < 8; ++n2) {
        const int d = n2 * 16 + li;
        const int vbyte = (d * 128 + kk2 * 64 + lg * 16) ^ ((d & 7) << 4);
        const short8v vf = *(const short8v*)((const char*)Vl + vbyte);
        oa[0][n2] = __builtin_amdgcn_mfma_f32_16x16x32_bf16(vf, pf[0][kk2], oa[0][n2], 0, 0, 0);
        oa[1][n2] = __builtin_amdgcn_mfma_f32_16x16x32_bf16(vf, pf[1][kk2], oa[1][n2], 0, 0, 0);
      }
    }
    __builtin_amdgcn_s_barrier();
    if (kt + 1 < nt) STAGE_V(kt + 1);
  }

  // epilogue: oa[m][n2][j] = O[q=qrow0+m*16+li][d=n2*16+lg*4+j].
  // Stage per-wave into (reused) Kl with swizzle, read back coalesced.
  {
    char* Ol = (char*)Kl + wave * 8192;   // [32 q'][128 d] u16, swizzled
#pragma unroll
    for (int m = 0; m < 2; ++m) {
      const float inv = 1.0f / lSum[m];
      const int q_ = m * 16 + li;
#pragma unroll
      for (int n2 = 0; n2 < 8; ++n2) {
        unsigned lo = cvt_pk_bf16(oa[m][n2][0] * inv, oa[m][n2][1] * inv);
        unsigned hi = cvt_pk_bf16(oa[m][n2][2] * inv, oa[m][n2][3] * inv);
        const int byteo = (q_ * 256 + n2 * 32 + lg * 8) ^ ((q_ & 7) << 4);
        uint2 pr; pr.x = lo; pr.y = hi;
        *(uint2*)(Ol + byteo) = pr;
      }
    }
    asm volatile("s_waitcnt lgkmcnt(0)" ::: "memory");
#pragma unroll
    for (int rr = 0; rr < 4; ++rr) {
      const int r = rr * 8 + (lane >> 3);
      const size_t grow = (size_t)(b * 2048 + qt * 128 + wave * 32 + r) * 2048 + h * 128;
#pragma unroll
      for (int s2 = 0; s2 < 2; ++s2) {
        const int byteo = (r * 256 + (lane & 7) * 32 + s2 * 16) ^ ((r & 7) << 4);
        const u16x8 val = *(const u16x8*)(Ol + byteo);
        *(u16x8*)&attn_out[grow + (lane & 7) * 16 + s2 * 8] = val;
      }
    }
  }
#undef STAGE_K
#undef STAGE_V
}

// ---------------- launch ----------------
extern "C" void kernel_launch(void* const* d_in, const int* in_sizes, int n_in,
                              void* d_out, int out_size, void* d_ws, size_t ws_size,
                              hipStream_t stream) {
  const float* x    = (const float*)d_in[0];   // [2,2048,2048]
  const int*   kpm  = (const int*)d_in[1];     // [2,2048]
  const float* wqkv = (const float*)d_in[2];   // [6144,2048]
  const float* bqkv = (const float*)d_in[3];   // [6144]
  const float* wout = (const float*)d_in[4];   // [2048,2048]
  const float* bout = (const float*)d_in[5];   // [2048]
  float* out = (float*)d_out;

  char* ws = (char*)d_ws;
  u16* xbf   = (u16*)(ws);                    // 16 MiB: x bf16 [4096,2048]
  u16* wqbf  = (u16*)(ws + (16u << 20));      // 24 MiB: Wqkv bf16 [6144,2048]
  u16* wobf  = (u16*)(ws + (40u << 20));      //  8 MiB: out_w bf16 [2048,2048]
  u16* qkvb  = (u16*)(ws + (48u << 20));      // 48 MiB: qkv bf16 [4096,6144]
  u16* vtb   = (u16*)(ws + (96u << 20));      // 16 MiB: V^T bf16 [32,128,2048]
  u16* attnb = (u16*)(ws + (112u << 20));     // 16 MiB: attn bf16 [4096,2048]

  f2bf_kernel<<<1024, 256, 0, stream>>>(x,    xbf,  4096 * 2048 / 4);
  f2bf_kernel<<<1024, 256, 0, stream>>>(wqkv, wqbf, 6144 * 2048 / 4);
  f2bf_kernel<<<1024, 256, 0, stream>>>(wout, wobf, 2048 * 2048 / 4);

  gemm_bt<1><<<dim3(48, 32), 256, 0, stream>>>(xbf, wqbf, bqkv, qkvb, 4096, 6144, 2048);
  transpose_v<<<dim3(32, 32), 256, 0, stream>>>(qkvb, vtb);
  attn_fused<<<dim3(16, 32), 256, 0, stream>>>(qkvb, vtb, kpm, attnb);
  gemm_bt<0><<<dim3(16, 32), 256, 0, stream>>>(attnb, wobf, bout, out, 4096, 2048, 2048);
}

// Round 5
// 315.464 us; speedup vs baseline: 1.3448x; 1.0833x over previous
//
#include <hip/hip_runtime.h>
#include <cstdint>

// Problem constants: B=2, S=2048, D=2048, H=16, DH=128
typedef unsigned short u16;
typedef __attribute__((ext_vector_type(8))) short short8v;       // 8 x bf16 (MFMA A/B frag)
typedef __attribute__((ext_vector_type(8))) unsigned short u16x8;
typedef __attribute__((ext_vector_type(4))) float floatx4;       // MFMA C/D frag

typedef unsigned int __attribute__((address_space(1))) as1_u32;
typedef unsigned int __attribute__((address_space(3))) as3_u32;

__device__ __forceinline__ u16 f2bf(float f) {
  union { float f; unsigned u; } v; v.f = f;
  unsigned r = v.u + 0x7FFFu + ((v.u >> 16) & 1u);   // RNE
  return (u16)(r >> 16);
}

__device__ __forceinline__ unsigned cvt_pk_bf16(float lo, float hi) {
  unsigned r;
  asm("v_cvt_pk_bf16_f32 %0, %1, %2" : "=v"(r) : "v"(lo), "v"(hi));
  return r;
}

__device__ __forceinline__ void gload16(void* lds, const void* g) {
  __builtin_amdgcn_global_load_lds((as1_u32*)(uintptr_t)g, (as3_u32*)(uintptr_t)lds, 16, 0, 0);
}

// ---------------- fp32 -> bf16 conversion ----------------
__global__ __launch_bounds__(256) void f2bf_kernel(const float* __restrict__ in,
                                                   u16* __restrict__ out, int n4) {
  int i = blockIdx.x * 256 + threadIdx.x;
  const int stride = gridDim.x * 256;
  for (; i < n4; i += stride) {
    float4 v = ((const float4*)in)[i];
    ushort4 o;
    o.x = f2bf(v.x); o.y = f2bf(v.y); o.z = f2bf(v.z); o.w = f2bf(v.w);
    ((ushort4*)out)[i] = o;
  }
}

// ---------------- 256x256 8-phase GEMM: C = A[M,K] @ B[N,K]^T + bias ----------------
// 512 thr = 8 waves (2M x 4N); BK=64; per-wave out 128x64 (acc[8][4]).
// LDS 128KiB: [2 slots][A0,A1,B0,B1][128 rows x 64 k] bf16, XOR-swizzled
// (kbyte ^= (row&7)<<4; global source pre-swizzled, linear gload_lds dest).
// Phase p of tile t: {ds_read subtile, stage 1 half-tile, barrier, lgkmcnt(0),
// setprio(1), 16 MFMA, setprio(0), barrier}. Stage order: ph0->A0(t+1),
// ph1->A1(t+1), ph2->B0(t+2), ph3->B1(t+2) (B regions of cur slot are dead
// after ph0's reads). Boundary: vmcnt(4) at ph3 keeps B(t+2) in flight.
template <int OUT_BF16>
__global__ __launch_bounds__(512, 2)
void gemm256(const u16* __restrict__ A, const u16* __restrict__ B,
             const float* __restrict__ bias, void* __restrict__ C,
             int M, int N, int K) {
  __shared__ u16 lds[2][4][8192];   // 128 KiB
  const int tid = threadIdx.x;
  const int wid = tid >> 6, lane = tid & 63;
  const int wr = wid >> 2, wc = wid & 3;
  const int li = lane & 15, lg = lane >> 4;
  const int brow = blockIdx.y * 256, bcol = blockIdx.x * 256;
  const int NT = K >> 6;

  // staging sources: linear LDS byte L=row*128+kb holds logical k-byte kb^((row&7)<<4)
  const int rowL = tid >> 3;                                   // 0..63
  const int klog = ((((tid & 7) << 4) ^ ((rowL & 7) << 4)) >> 1);
  const u16* aS = A + (size_t)(brow + rowL) * K + klog;
  const u16* bS = B + (size_t)(bcol + rowL) * K + klog;

#define STG(slot, reg, src, hh, kt_)                                            \
  {                                                                             \
    const u16* s_ = (src) + (size_t)((hh) * 128) * K + (kt_) * 64;              \
    gload16((char*)&lds[slot][reg][0] + tid * 16, s_);                          \
    gload16((char*)&lds[slot][reg][0] + 8192 + tid * 16, s_ + (size_t)64 * K);  \
  }

  floatx4 acc[8][4];
#pragma unroll
  for (int m = 0; m < 8; ++m)
#pragma unroll
    for (int n = 0; n < 4; ++n) acc[m][n] = floatx4{0.f, 0.f, 0.f, 0.f};

  // swizzled k-offsets for ds_read (row&7 == li&7 for all frag rows)
  const int kx0 = (lg * 16) ^ ((li & 7) << 4);
  const int kx1 = (64 + lg * 16) ^ ((li & 7) << 4);
  const int ar0 = li * 128;                    // + m*2048
  const int bc0 = ((wc & 1) * 64 + li) * 128;  // + n*2048

  // prologue: tile0 (4 half-tiles) + B(1) (2 half-tiles); keep B(1) in flight
  STG(0, 0, aS, 0, 0);
  STG(0, 1, aS, 1, 0);
  STG(0, 2, bS, 0, 0);
  STG(0, 3, bS, 1, 0);
  STG(1, 2, bS, 0, 1);
  STG(1, 3, bS, 1, 1);
  asm volatile("s_waitcnt vmcnt(4)" ::: "memory");
  __builtin_amdgcn_s_barrier();

  for (int t = 0; t < NT; ++t) {
    const int cur = t & 1;
    const char* Ab = (const char*)&lds[cur][wr][0];
    const char* Bb = (const char*)&lds[cur][2 + (wc >> 1)][0];

    // ---- phase 0: read all B frags + A[0..1]; stage A0(t+1)
    short8v bf[4][2], af[2][2];
#pragma unroll
    for (int n = 0; n < 4; ++n) {
      bf[n][0] = *(const short8v*)(Bb + bc0 + n * 2048 + kx0);
      bf[n][1] = *(const short8v*)(Bb + bc0 + n * 2048 + kx1);
    }
#pragma unroll
    for (int mm = 0; mm < 2; ++mm) {
      af[mm][0] = *(const short8v*)(Ab + ar0 + mm * 2048 + kx0);
      af[mm][1] = *(const short8v*)(Ab + ar0 + mm * 2048 + kx1);
    }
    if (t + 1 < NT) STG(cur ^ 1, 0, aS, 0, t + 1);
    asm volatile("s_waitcnt lgkmcnt(8)" ::: "memory");
    __builtin_amdgcn_s_barrier();
    asm volatile("s_waitcnt lgkmcnt(0)" ::: "memory");
    __builtin_amdgcn_s_setprio(1);
#pragma unroll
    for (int mm = 0; mm < 2; ++mm)
#pragma unroll
      for (int ks = 0; ks < 2; ++ks)
#pragma unroll
        for (int n = 0; n < 4; ++n)
          acc[mm][n] = __builtin_amdgcn_mfma_f32_16x16x32_bf16(af[mm][ks], bf[n][ks], acc[mm][n], 0, 0, 0);
    __builtin_amdgcn_s_setprio(0);
    __builtin_amdgcn_s_barrier();

    // ---- phases 1..3: read A[2p..2p+1]; stage A1(t+1)/B0(t+2)/B1(t+2)
#pragma unroll
    for (int ph = 1; ph < 4; ++ph) {
      const int m0 = ph * 2;
      short8v a2[2][2];
#pragma unroll
      for (int mm = 0; mm < 2; ++mm) {
        a2[mm][0] = *(const short8v*)(Ab + ar0 + (m0 + mm) * 2048 + kx0);
        a2[mm][1] = *(const short8v*)(Ab + ar0 + (m0 + mm) * 2048 + kx1);
      }
      if (ph == 1)      { if (t + 1 < NT) STG(cur ^ 1, 1, aS, 1, t + 1); }
      else if (ph == 2) { if (t + 2 < NT) STG(cur, 2, bS, 0, t + 2); }
      else              { if (t + 2 < NT) STG(cur, 3, bS, 1, t + 2); }
      __builtin_amdgcn_s_barrier();
      asm volatile("s_waitcnt lgkmcnt(0)" ::: "memory");
      __builtin_amdgcn_s_setprio(1);
#pragma unroll
      for (int mm = 0; mm < 2; ++mm)
#pragma unroll
        for (int ks = 0; ks < 2; ++ks)
#pragma unroll
          for (int n = 0; n < 4; ++n)
            acc[m0 + mm][n] = __builtin_amdgcn_mfma_f32_16x16x32_bf16(a2[mm][ks], bf[n][ks], acc[m0 + mm][n], 0, 0, 0);
      __builtin_amdgcn_s_setprio(0);
      if (ph == 3) {
        if (t + 2 < NT) asm volatile("s_waitcnt vmcnt(4)" ::: "memory");
        else            asm volatile("s_waitcnt vmcnt(0)" ::: "memory");
      }
      __builtin_amdgcn_s_barrier();
    }
  }
#undef STG

  // epilogue: C row = brow + wr*128 + m*16 + lg*4 + j, col = bcol + wc*64 + n*16 + li
  const int crow0 = brow + wr * 128 + lg * 4;
  const int ccol0 = bcol + wc * 64 + li;
#pragma unroll
  for (int n = 0; n < 4; ++n) {
    const float bv = bias[ccol0 + n * 16];
#pragma unroll
    for (int m = 0; m < 8; ++m) {
#pragma unroll
      for (int j = 0; j < 4; ++j) {
        const float v = acc[m][n][j] + bv;
        const size_t idx = (size_t)(crow0 + m * 16 + j) * N + (ccol0 + n * 16);
        if (OUT_BF16) ((u16*)C)[idx] = f2bf(v);
        else          ((float*)C)[idx] = v;
      }
    }
  }
}

// ---------------- V transpose: qkv V-part [b,s,h,dh] -> vt [b,h,dh,s] ----------------
__global__ __launch_bounds__(256)
void transpose_v(const u16* __restrict__ qkv, u16* __restrict__ vt) {
  __shared__ u16 T[64][136];
  const int st = blockIdx.x, bh = blockIdx.y;
  const int b = bh >> 4, h = bh & 15;
  const int tid = threadIdx.x;
  const u16* src = qkv + (size_t)(b * 2048 + st * 64) * 6144 + 4096 + h * 128;
  u16* dst = vt + (size_t)bh * 128 * 2048 + st * 64;
#pragma unroll
  for (int p = 0; p < 4; ++p) {
    const int e = (p * 256 + tid) * 8;
    const int r = e >> 7, c = e & 127;
    *(u16x8*)&T[r][c] = *(const u16x8*)&src[(size_t)r * 6144 + c];
  }
  __syncthreads();
#pragma unroll
  for (int p = 0; p < 4; ++p) {
    const int e = (p * 256 + tid) * 8;
    const int dh = e >> 6, s0 = e & 63;
    u16x8 o;
#pragma unroll
    for (int j = 0; j < 8; ++j) o[j] = T[s0 + j][dh];
    *(u16x8*)&dst[(size_t)dh * 2048 + s0] = o;
  }
}

// ---------------- fused causal flash attention (swapped-operand, reg softmax) -------
__global__ __launch_bounds__(256, 2)
void attn_fused(const u16* __restrict__ qkv, const u16* __restrict__ vt,
                const int* __restrict__ kpm, u16* __restrict__ attn_out) {
  constexpr int S = 2048, DQ = 6144;
  __shared__ u16 Kl[2][64 * 128];   // 32KB, double-buffered; reused as O-staging
  __shared__ u16 Vl[128 * 64];      // 16KB
  __shared__ float mskf[2048];      // 8KB additive pad penalties
  __shared__ int s_any;
  const int bx = blockIdx.x, by = blockIdx.y;
  const int qt = ((by >> 4) & 1) ? bx : (15 - bx);
  const int bh = by;
  const int b = bh >> 4, h = bh & 15;
  const int tid = threadIdx.x, wave = tid >> 6, lane = tid & 63;
  const int lg = lane >> 4, li = lane & 15;
  const int qrow0 = qt * 128 + wave * 32;

  const u16* Qb = qkv + (size_t)b * S * DQ + h * 128;
  const u16* Kb = Qb + 2048;
  const u16* Vtb = vt + (size_t)bh * 128 * 2048;
  const int* mrow = kpm + b * S;

  if (tid == 0) s_any = 0;
  __syncthreads();
  {
    int a = 0;
    for (int j = tid; j < 2048; j += 256) {
      const int mv = mrow[j];
      mskf[j] = mv ? 0.f : -1.0e9f;
      if (mv && j <= qt * 128) a = 1;
    }
    if (a) s_any = 1;
  }
  __syncthreads();
  const int anyv = s_any;
  const int nt = anyv ? (2 * qt + 2) : 32;
  const int causalFromW = anyv ? (qrow0 >> 6) : 0;

  short8v qb[2][4];
#pragma unroll
  for (int m = 0; m < 2; ++m) {
    const u16* qp = Qb + (size_t)(qrow0 + m * 16 + li) * DQ + lg * 8;
#pragma unroll
    for (int kk = 0; kk < 4; ++kk) qb[m][kk] = *(const short8v*)(qp + kk * 32);
  }
  asm volatile("s_waitcnt vmcnt(0)" ::: "memory");

  float mM[2], lSum[2];
  floatx4 oa[2][8];
#pragma unroll
  for (int m = 0; m < 2; ++m) {
    mM[m] = -3.0e38f; lSum[m] = 0.f;
#pragma unroll
    for (int n = 0; n < 8; ++n) oa[m][n] = floatx4{0.f, 0.f, 0.f, 0.f};
  }

  const u16* kSrc[4]; const u16* vSrc[4];
#pragma unroll
  for (int i = 0; i < 4; ++i) {
    const int L = i * 4096 + tid * 16;
    const int r = L >> 8;
    const int c = ((L & 255) ^ ((r & 7) << 4)) >> 1;
    kSrc[i] = Kb + (size_t)r * DQ + c;
    const int d = L >> 7;
    const int sv = ((L & 127) ^ ((d & 7) << 4)) >> 1;
    vSrc[i] = Vtb + (size_t)d * 2048 + sv;
  }

#define STAGE_K(buf, kt_)                                                      \
  {                                                                            \
    const int kv0_ = (kt_) * 64;                                               \
    _Pragma("unroll")                                                          \
    for (int i = 0; i < 4; ++i)                                                \
      gload16((char*)Kl + (buf) * 16384 + i * 4096 + tid * 16,                 \
              kSrc[i] + (size_t)kv0_ * DQ);                                    \
  }
#define STAGE_V(kt_)                                                           \
  {                                                                            \
    const int kv0_ = (kt_) * 64;                                               \
    _Pragma("unroll")                                                          \
    for (int i = 0; i < 4; ++i)                                                \
      gload16((char*)Vl + i * 4096 + tid * 16, vSrc[i] + kv0_);                \
  }

  const float scale = 0.08838834764831845f;  // 1/sqrt(128)

  STAGE_K(0, 0);
  STAGE_V(0);

  for (int kt = 0; kt < nt; ++kt) {
    const int cur = kt & 1;
    const int kv0 = kt * 64;
    if (kt + 1 < nt) {
      STAGE_K(cur ^ 1, kt + 1);
      asm volatile("s_waitcnt vmcnt(8)" ::: "memory");
    } else {
      asm volatile("s_waitcnt vmcnt(4)" ::: "memory");
    }
    __builtin_amdgcn_s_barrier();

    const char* Kcur = (const char*)Kl + cur * 16384;

    floatx4 sc[2][4];
#pragma unroll
    for (int n = 0; n < 4; ++n) { sc[0][n] = floatx4{0,0,0,0}; sc[1][n] = floatx4{0,0,0,0}; }
#pragma unroll
    for (int n = 0; n < 4; ++n) {
      const int r = n * 16 + li;
#pragma unroll
      for (int kk = 0; kk < 4; ++kk) {
        const int byteo = (r * 256 + kk * 64 + lg * 16) ^ ((r & 7) << 4);
        const short8v kf = *(const short8v*)(Kcur + byteo);
        sc[0][n] = __builtin_amdgcn_mfma_f32_16x16x32_bf16(kf, qb[0][kk], sc[0][n], 0, 0, 0);
        sc[1][n] = __builtin_amdgcn_mfma_f32_16x16x32_bf16(kf, qb[1][kk], sc[1][n], 0, 0, 0);
      }
    }

    floatx4 pbv[4];
#pragma unroll
    for (int n = 0; n < 4; ++n)
      pbv[n] = *(const floatx4*)&mskf[kv0 + n * 16 + lg * 4];
    const bool cz = (kt >= causalFromW);

    short8v pf[2][2];
#pragma unroll
    for (int m = 0; m < 2; ++m) {
      const int q_l = qrow0 + m * 16 + li;
      float tmax = -3.0e38f;
#pragma unroll
      for (int n = 0; n < 4; ++n)
#pragma unroll
        for (int j = 0; j < 4; ++j) {
          float s = sc[m][n][j] * scale + pbv[n][j];
          if (cz && (kv0 + n * 16 + lg * 4 + j > q_l)) s -= 1.0e9f;
          sc[m][n][j] = s;
          tmax = fmaxf(tmax, s);
        }
      tmax = fmaxf(tmax, __shfl_xor(tmax, 16));
      tmax = fmaxf(tmax, __shfl_xor(tmax, 32));
      const float mnew = fmaxf(mM[m], tmax);
      const float f = __expf(mM[m] - mnew);
      mM[m] = mnew;
      float rs = 0.f;
#pragma unroll
      for (int n = 0; n < 4; ++n)
#pragma unroll
        for (int j = 0; j < 4; ++j) {
          const float e = __expf(sc[m][n][j] - mnew);
          sc[m][n][j] = e; rs += e;
        }
      rs += __shfl_xor(rs, 16);
      rs += __shfl_xor(rs, 32);
      lSum[m] = lSum[m] * f + rs;
#pragma unroll
      for (int n2 = 0; n2 < 8; ++n2) oa[m][n2] *= f;

      unsigned w32[4][2];
#pragma unroll
      for (int n = 0; n < 4; ++n) {
        w32[n][0] = cvt_pk_bf16(sc[m][n][0], sc[m][n][1]);
        w32[n][1] = cvt_pk_bf16(sc[m][n][2], sc[m][n][3]);
      }
      union PF { short8v s; unsigned w[4]; } pfu[2];
#pragma unroll
      for (int kk2 = 0; kk2 < 2; ++kk2) {
#pragma unroll
        for (int hh = 0; hh < 2; ++hh) {
          unsigned u = w32[2 * kk2][hh], v = w32[2 * kk2 + 1][hh];
          asm volatile("v_permlane32_swap_b32 %0, %1" : "+v"(u), "+v"(v));
          asm volatile("v_permlane16_swap_b32 %0, %1" : "+v"(u), "+v"(v));
          pfu[kk2].w[hh] = u;
          pfu[kk2].w[2 + hh] = v;
        }
      }
      pf[m][0] = pfu[0].s;
      pf[m][1] = pfu[1].s;
    }

    if (kt + 1 < nt) asm volatile("s_waitcnt vmcnt(4)" ::: "memory");
    else             asm volatile("s_waitcnt vmcnt(0)" ::: "memory");
    __builtin_amdgcn_s_barrier();

#pragma unroll
    for (int kk2 = 0; kk2 < 2; ++kk2) {
#pragma unroll
      for (int n2 = 0; n2 < 8; ++n2) {
        const int d = n2 * 16 + li;
        const int vbyte = (d * 128 + kk2 * 64 + lg * 16) ^ ((d & 7) << 4);
        const short8v vf = *(const short8v*)((const char*)Vl + vbyte);
        oa[0][n2] = __builtin_amdgcn_mfma_f32_16x16x32_bf16(vf, pf[0][kk2], oa[0][n2], 0, 0, 0);
        oa[1][n2] = __builtin_amdgcn_mfma_f32_16x16x32_bf16(vf, pf[1][kk2], oa[1][n2], 0, 0, 0);
      }
    }
    __builtin_amdgcn_s_barrier();
    if (kt + 1 < nt) STAGE_V(kt + 1);
  }

  {
    char* Ol = (char*)Kl + wave * 8192;
#pragma unroll
    for (int m = 0; m < 2; ++m) {
      const float inv = 1.0f / lSum[m];
      const int q_ = m * 16 + li;
#pragma unroll
      for (int n2 = 0; n2 < 8; ++n2) {
        unsigned lo = cvt_pk_bf16(oa[m][n2][0] * inv, oa[m][n2][1] * inv);
        unsigned hi = cvt_pk_bf16(oa[m][n2][2] * inv, oa[m][n2][3] * inv);
        const int byteo = (q_ * 256 + n2 * 32 + lg * 8) ^ ((q_ & 7) << 4);
        uint2 pr; pr.x = lo; pr.y = hi;
        *(uint2*)(Ol + byteo) = pr;
      }
    }
    asm volatile("s_waitcnt lgkmcnt(0)" ::: "memory");
#pragma unroll
    for (int rr = 0; rr < 4; ++rr) {
      const int r = rr * 8 + (lane >> 3);
      const size_t grow = (size_t)(b * 2048 + qt * 128 + wave * 32 + r) * 2048 + h * 128;
#pragma unroll
      for (int s2 = 0; s2 < 2; ++s2) {
        const int byteo = (r * 256 + (lane & 7) * 32 + s2 * 16) ^ ((r & 7) << 4);
        const u16x8 val = *(const u16x8*)(Ol + byteo);
        *(u16x8*)&attn_out[grow + (lane & 7) * 16 + s2 * 8] = val;
      }
    }
  }
#undef STAGE_K
#undef STAGE_V
}

// ---------------- launch ----------------
extern "C" void kernel_launch(void* const* d_in, const int* in_sizes, int n_in,
                              void* d_out, int out_size, void* d_ws, size_t ws_size,
                              hipStream_t stream) {
  const float* x    = (const float*)d_in[0];   // [2,2048,2048]
  const int*   kpm  = (const int*)d_in[1];     // [2,2048]
  const float* wqkv = (const float*)d_in[2];   // [6144,2048]
  const float* bqkv = (const float*)d_in[3];   // [6144]
  const float* wout = (const float*)d_in[4];   // [2048,2048]
  const float* bout = (const float*)d_in[5];   // [2048]
  float* out = (float*)d_out;

  char* ws = (char*)d_ws;
  u16* xbf   = (u16*)(ws);                    // 16 MiB: x bf16 [4096,2048]
  u16* wqbf  = (u16*)(ws + (16u << 20));      // 24 MiB: Wqkv bf16 [6144,2048]
  u16* wobf  = (u16*)(ws + (40u << 20));      //  8 MiB: out_w bf16 [2048,2048]
  u16* qkvb  = (u16*)(ws + (48u << 20));      // 48 MiB: qkv bf16 [4096,6144]
  u16* vtb   = (u16*)(ws + (96u << 20));      // 16 MiB: V^T bf16 [32,128,2048]
  u16* attnb = (u16*)(ws + (112u << 20));     // 16 MiB: attn bf16 [4096,2048]

  f2bf_kernel<<<1024, 256, 0, stream>>>(x,    xbf,  4096 * 2048 / 4);
  f2bf_kernel<<<1024, 256, 0, stream>>>(wqkv, wqbf, 6144 * 2048 / 4);
  f2bf_kernel<<<1024, 256, 0, stream>>>(wout, wobf, 2048 * 2048 / 4);

  gemm256<1><<<dim3(24, 16), 512, 0, stream>>>(xbf, wqbf, bqkv, qkvb, 4096, 6144, 2048);
  transpose_v<<<dim3(32, 32), 256, 0, stream>>>(qkvb, vtb);
  attn_fused<<<dim3(16, 32), 256, 0, stream>>>(qkvb, vtb, kpm, attnb);
  gemm256<0><<<dim3(8, 16), 512, 0, stream>>>(attnb, wobf, bout, out, 4096, 2048, 2048);
}

// Round 6
// 290.589 us; speedup vs baseline: 1.4600x; 1.0856x over previous
//
#include <hip/hip_runtime.h>
#include <cstdint>

// Problem constants: B=2, S=2048, D=2048, H=16, DH=128
typedef unsigned short u16;
typedef __attribute__((ext_vector_type(8))) short short8v;       // 8 x bf16 (MFMA A/B frag)
typedef __attribute__((ext_vector_type(8))) unsigned short u16x8;
typedef __attribute__((ext_vector_type(4))) float floatx4;       // MFMA C/D frag

typedef unsigned int __attribute__((address_space(1))) as1_u32;
typedef unsigned int __attribute__((address_space(3))) as3_u32;

__device__ __forceinline__ u16 f2bf(float f) {
  union { float f; unsigned u; } v; v.f = f;
  unsigned r = v.u + 0x7FFFu + ((v.u >> 16) & 1u);   // RNE
  return (u16)(r >> 16);
}

__device__ __forceinline__ unsigned cvt_pk_bf16(float lo, float hi) {
  unsigned r;
  asm("v_cvt_pk_bf16_f32 %0, %1, %2" : "=v"(r) : "v"(lo), "v"(hi));
  return r;
}

__device__ __forceinline__ void gload16(void* lds, const void* g) {
  __builtin_amdgcn_global_load_lds((as1_u32*)(uintptr_t)g, (as3_u32*)(uintptr_t)lds, 16, 0, 0);
}

// ---------------- fp32 -> bf16 conversion ----------------
__global__ __launch_bounds__(256) void f2bf_kernel(const float* __restrict__ in,
                                                   u16* __restrict__ out, int n4) {
  int i = blockIdx.x * 256 + threadIdx.x;
  const int stride = gridDim.x * 256;
  for (; i < n4; i += stride) {
    float4 v = ((const float4*)in)[i];
    ushort4 o;
    o.x = f2bf(v.x); o.y = f2bf(v.y); o.z = f2bf(v.z); o.w = f2bf(v.w);
    ((ushort4*)out)[i] = o;
  }
}

// ---------------- 128x256 2-phase GEMM: C = A[M,K] @ B[N,K]^T + bias ----------------
// 512 thr = 8 waves (2M x 4N), per-wave 64x64 out (acc[4][4]); BK=64.
// LDS 96KiB: A[2][128][64] + B[2][256][64] bf16, XOR-swizzled (kbyte ^= (row&7)<<4,
// pre-swizzled global source, linear gload_lds dest). Grid is 1D, XCD-bijective
// swizzled (nwg%8==0), bm-fastest so each XCD chunk keeps ~3 B-panels L2-resident.
// Per K-tile t: ph0 {12 ds_read (all B + A[0..1]), stage A(t+1); bar; lgkm0;
// 16 MFMA; bar}, ph1 {4 ds_read (A[2..3]), stage B(t+2) into freed B[cur];
// bar; lgkm0; 16 MFMA; vmcnt(4); bar}. FIFO at tile end: B(t+1)4,A(t+1)2,B(t+2)4
// -> vmcnt(4) drains exactly B(t+1)+A(t+1). Prologue A0,B0,B1 -> vmcnt(4).
template <int OUT_BF16>
__global__ __launch_bounds__(512, 2)
void gemm_bt2(const u16* __restrict__ A, const u16* __restrict__ B,
              const float* __restrict__ bias, void* __restrict__ C,
              int M, int N, int K) {
  __shared__ u16 Al[2][128 * 64];   // 32KB
  __shared__ u16 Bl[2][256 * 64];   // 64KB
  const int tid = threadIdx.x;
  const int wid = tid >> 6, lane = tid & 63;
  const int wr = wid >> 2, wc = wid & 3;
  const int li = lane & 15, lg = lane >> 4;
  const int nwg = gridDim.x;
  const int bid = blockIdx.x;
  const int swz = (bid & 7) * (nwg >> 3) + (bid >> 3);   // XCD-bijective
  const int mcnt = M >> 7;
  const int bm = swz % mcnt, bn = swz / mcnt;            // bm-fastest
  const int brow = bm * 128, bcol = bn * 256;
  const int NT = K >> 6;

  // staging: linear LDS byte L = row*128 + kb holds logical k-byte kb^((row&7)<<4)
  const int rowL = tid >> 3;                              // 0..63 (row & 7 invariant under +64)
  const int klog = ((((tid & 7) << 4) ^ ((rowL & 7) << 4)) >> 1);
  const u16* aS = A + (size_t)(brow + rowL) * K + klog;
  const u16* bS = B + (size_t)(bcol + rowL) * K + klog;

#define STG_A(slot, kt_)                                                        \
  {                                                                             \
    const u16* s_ = aS + (kt_) * 64;                                            \
    gload16((char*)&Al[slot][0] + tid * 16, s_);                                \
    gload16((char*)&Al[slot][0] + 8192 + tid * 16, s_ + (size_t)64 * K);        \
  }
#define STG_B(slot, kt_)                                                        \
  {                                                                             \
    const u16* s_ = bS + (kt_) * 64;                                            \
    _Pragma("unroll")                                                           \
    for (int c_ = 0; c_ < 4; ++c_)                                              \
      gload16((char*)&Bl[slot][0] + c_ * 8192 + tid * 16,                       \
              s_ + (size_t)(c_ * 64) * K);                                      \
  }

  floatx4 acc[4][4];
#pragma unroll
  for (int m = 0; m < 4; ++m)
#pragma unroll
    for (int n = 0; n < 4; ++n) acc[m][n] = floatx4{0.f, 0.f, 0.f, 0.f};

  const int kx0 = (lg * 16) ^ ((li & 7) << 4);
  const int kx1 = (64 + lg * 16) ^ ((li & 7) << 4);
  const int ar0 = (wr * 64 + li) * 128;    // + m*2048
  const int bc0 = (wc * 64 + li) * 128;    // + n*2048

  STG_A(0, 0);
  STG_B(0, 0);
  STG_B(1, 1);
  asm volatile("s_waitcnt vmcnt(4)" ::: "memory");   // A0,B0 done; B1 in flight
  __builtin_amdgcn_s_barrier();

  for (int t = 0; t < NT; ++t) {
    const int cur = t & 1;
    const char* Ab = (const char*)&Al[cur][0];
    const char* Bb = (const char*)&Bl[cur][0];

    // ---- phase 0: all B frags + A[0..1]; stage A(t+1)
    short8v bf[4][2], af[2][2];
#pragma unroll
    for (int n = 0; n < 4; ++n) {
      bf[n][0] = *(const short8v*)(Bb + bc0 + n * 2048 + kx0);
      bf[n][1] = *(const short8v*)(Bb + bc0 + n * 2048 + kx1);
    }
#pragma unroll
    for (int mm = 0; mm < 2; ++mm) {
      af[mm][0] = *(const short8v*)(Ab + ar0 + mm * 2048 + kx0);
      af[mm][1] = *(const short8v*)(Ab + ar0 + mm * 2048 + kx1);
    }
    if (t + 1 < NT) STG_A(cur ^ 1, t + 1);
    asm volatile("s_waitcnt lgkmcnt(8)" ::: "memory");
    __builtin_amdgcn_s_barrier();
    asm volatile("s_waitcnt lgkmcnt(0)" ::: "memory");
    __builtin_amdgcn_s_setprio(1);
#pragma unroll
    for (int mm = 0; mm < 2; ++mm)
#pragma unroll
      for (int ks = 0; ks < 2; ++ks)
#pragma unroll
        for (int n = 0; n < 4; ++n)
          acc[mm][n] = __builtin_amdgcn_mfma_f32_16x16x32_bf16(af[mm][ks], bf[n][ks], acc[mm][n], 0, 0, 0);
    __builtin_amdgcn_s_setprio(0);
    __builtin_amdgcn_s_barrier();

    // ---- phase 1: A[2..3]; stage B(t+2) into freed B[cur]
    short8v a2[2][2];
#pragma unroll
    for (int mm = 0; mm < 2; ++mm) {
      a2[mm][0] = *(const short8v*)(Ab + ar0 + (2 + mm) * 2048 + kx0);
      a2[mm][1] = *(const short8v*)(Ab + ar0 + (2 + mm) * 2048 + kx1);
    }
    if (t + 2 < NT) STG_B(cur, t + 2);
    __builtin_amdgcn_s_barrier();
    asm volatile("s_waitcnt lgkmcnt(0)" ::: "memory");
    __builtin_amdgcn_s_setprio(1);
#pragma unroll
    for (int mm = 0; mm < 2; ++mm)
#pragma unroll
      for (int ks = 0; ks < 2; ++ks)
#pragma unroll
        for (int n = 0; n < 4; ++n)
          acc[2 + mm][n] = __builtin_amdgcn_mfma_f32_16x16x32_bf16(a2[mm][ks], bf[n][ks], acc[2 + mm][n], 0, 0, 0);
    __builtin_amdgcn_s_setprio(0);
    if (t + 2 < NT) asm volatile("s_waitcnt vmcnt(4)" ::: "memory");
    else            asm volatile("s_waitcnt vmcnt(0)" ::: "memory");
    __builtin_amdgcn_s_barrier();
  }
#undef STG_A
#undef STG_B

  // epilogue: row = brow + wr*64 + m*16 + lg*4 + j, col = bcol + wc*64 + n*16 + li
  const int crow0 = brow + wr * 64 + lg * 4;
  const int ccol0 = bcol + wc * 64 + li;
#pragma unroll
  for (int n = 0; n < 4; ++n) {
    const float bv = bias[ccol0 + n * 16];
#pragma unroll
    for (int m = 0; m < 4; ++m) {
#pragma unroll
      for (int j = 0; j < 4; ++j) {
        const float v = acc[m][n][j] + bv;
        const size_t idx = (size_t)(crow0 + m * 16 + j) * N + (ccol0 + n * 16);
        if (OUT_BF16) ((u16*)C)[idx] = f2bf(v);
        else          ((float*)C)[idx] = v;
      }
    }
  }
}

// ---------------- V transpose: qkv V-part [b,s,h,dh] -> vt [b,h,dh,s] ----------------
__global__ __launch_bounds__(256)
void transpose_v(const u16* __restrict__ qkv, u16* __restrict__ vt) {
  __shared__ u16 T[64][136];
  const int st = blockIdx.x, bh = blockIdx.y;
  const int b = bh >> 4, h = bh & 15;
  const int tid = threadIdx.x;
  const u16* src = qkv + (size_t)(b * 2048 + st * 64) * 6144 + 4096 + h * 128;
  u16* dst = vt + (size_t)bh * 128 * 2048 + st * 64;
#pragma unroll
  for (int p = 0; p < 4; ++p) {
    const int e = (p * 256 + tid) * 8;
    const int r = e >> 7, c = e & 127;
    *(u16x8*)&T[r][c] = *(const u16x8*)&src[(size_t)r * 6144 + c];
  }
  __syncthreads();
#pragma unroll
  for (int p = 0; p < 4; ++p) {
    const int e = (p * 256 + tid) * 8;
    const int dh = e >> 6, s0 = e & 63;
    u16x8 o;
#pragma unroll
    for (int j = 0; j < 8; ++j) o[j] = T[s0 + j][dh];
    *(u16x8*)&dst[(size_t)dh * 2048 + s0] = o;
  }
}

// ---------------- fused causal flash attention (swapped-operand, reg softmax) -------
__global__ __launch_bounds__(256, 2)
void attn_fused(const u16* __restrict__ qkv, const u16* __restrict__ vt,
                const int* __restrict__ kpm, u16* __restrict__ attn_out) {
  constexpr int S = 2048, DQ = 6144;
  __shared__ u16 Kl[2][64 * 128];   // 32KB, double-buffered; reused as O-staging
  __shared__ u16 Vl[128 * 64];      // 16KB
  __shared__ float mskf[2048];      // 8KB additive pad penalties
  __shared__ int s_any;
  const int bx = blockIdx.x, by = blockIdx.y;
  const int qt = ((by >> 4) & 1) ? bx : (15 - bx);
  const int bh = by;
  const int b = bh >> 4, h = bh & 15;
  const int tid = threadIdx.x, wave = tid >> 6, lane = tid & 63;
  const int lg = lane >> 4, li = lane & 15;
  const int qrow0 = qt * 128 + wave * 32;

  const u16* Qb = qkv + (size_t)b * S * DQ + h * 128;
  const u16* Kb = Qb + 2048;
  const u16* Vtb = vt + (size_t)bh * 128 * 2048;
  const int* mrow = kpm + b * S;

  if (tid == 0) s_any = 0;
  __syncthreads();
  {
    int a = 0;
    for (int j = tid; j < 2048; j += 256) {
      const int mv = mrow[j];
      mskf[j] = mv ? 0.f : -1.0e9f;
      if (mv && j <= qt * 128) a = 1;
    }
    if (a) s_any = 1;
  }
  __syncthreads();
  const int anyv = s_any;
  const int nt = anyv ? (2 * qt + 2) : 32;
  const int causalFromW = anyv ? (qrow0 >> 6) : 0;

  short8v qb[2][4];
#pragma unroll
  for (int m = 0; m < 2; ++m) {
    const u16* qp = Qb + (size_t)(qrow0 + m * 16 + li) * DQ + lg * 8;
#pragma unroll
    for (int kk = 0; kk < 4; ++kk) qb[m][kk] = *(const short8v*)(qp + kk * 32);
  }
  asm volatile("s_waitcnt vmcnt(0)" ::: "memory");

  float mM[2], lSum[2];
  floatx4 oa[2][8];
#pragma unroll
  for (int m = 0; m < 2; ++m) {
    mM[m] = -3.0e38f; lSum[m] = 0.f;
#pragma unroll
    for (int n = 0; n < 8; ++n) oa[m][n] = floatx4{0.f, 0.f, 0.f, 0.f};
  }

  const u16* kSrc[4]; const u16* vSrc[4];
#pragma unroll
  for (int i = 0; i < 4; ++i) {
    const int L = i * 4096 + tid * 16;
    const int r = L >> 8;
    const int c = ((L & 255) ^ ((r & 7) << 4)) >> 1;
    kSrc[i] = Kb + (size_t)r * DQ + c;
    const int d = L >> 7;
    const int sv = ((L & 127) ^ ((d & 7) << 4)) >> 1;
    vSrc[i] = Vtb + (size_t)d * 2048 + sv;
  }

#define STAGE_K(buf, kt_)                                                      \
  {                                                                            \
    const int kv0_ = (kt_) * 64;                                               \
    _Pragma("unroll")                                                          \
    for (int i = 0; i < 4; ++i)                                                \
      gload16((char*)Kl + (buf) * 16384 + i * 4096 + tid * 16,                 \
              kSrc[i] + (size_t)kv0_ * DQ);                                    \
  }
#define STAGE_V(kt_)                                                           \
  {                                                                            \
    const int kv0_ = (kt_) * 64;                                               \
    _Pragma("unroll")                                                          \
    for (int i = 0; i < 4; ++i)                                                \
      gload16((char*)Vl + i * 4096 + tid * 16, vSrc[i] + kv0_);                \
  }

  const float scale = 0.08838834764831845f;  // 1/sqrt(128)

  STAGE_K(0, 0);
  STAGE_V(0);

  for (int kt = 0; kt < nt; ++kt) {
    const int cur = kt & 1;
    const int kv0 = kt * 64;
    if (kt + 1 < nt) {
      STAGE_K(cur ^ 1, kt + 1);
      asm volatile("s_waitcnt vmcnt(8)" ::: "memory");
    } else {
      asm volatile("s_waitcnt vmcnt(4)" ::: "memory");
    }
    __builtin_amdgcn_s_barrier();

    const char* Kcur = (const char*)Kl + cur * 16384;

    floatx4 sc[2][4];
#pragma unroll
    for (int n = 0; n < 4; ++n) { sc[0][n] = floatx4{0,0,0,0}; sc[1][n] = floatx4{0,0,0,0}; }
#pragma unroll
    for (int n = 0; n < 4; ++n) {
      const int r = n * 16 + li;
#pragma unroll
      for (int kk = 0; kk < 4; ++kk) {
        const int byteo = (r * 256 + kk * 64 + lg * 16) ^ ((r & 7) << 4);
        const short8v kf = *(const short8v*)(Kcur + byteo);
        sc[0][n] = __builtin_amdgcn_mfma_f32_16x16x32_bf16(kf, qb[0][kk], sc[0][n], 0, 0, 0);
        sc[1][n] = __builtin_amdgcn_mfma_f32_16x16x32_bf16(kf, qb[1][kk], sc[1][n], 0, 0, 0);
      }
    }

    floatx4 pbv[4];
#pragma unroll
    for (int n = 0; n < 4; ++n)
      pbv[n] = *(const floatx4*)&mskf[kv0 + n * 16 + lg * 4];
    const bool cz = (kt >= causalFromW);

    short8v pf[2][2];
#pragma unroll
    for (int m = 0; m < 2; ++m) {
      const int q_l = qrow0 + m * 16 + li;
      float tmax = -3.0e38f;
#pragma unroll
      for (int n = 0; n < 4; ++n)
#pragma unroll
        for (int j = 0; j < 4; ++j) {
          float s = sc[m][n][j] * scale + pbv[n][j];
          if (cz && (kv0 + n * 16 + lg * 4 + j > q_l)) s -= 1.0e9f;
          sc[m][n][j] = s;
          tmax = fmaxf(tmax, s);
        }
      tmax = fmaxf(tmax, __shfl_xor(tmax, 16));
      tmax = fmaxf(tmax, __shfl_xor(tmax, 32));
      const float mnew = fmaxf(mM[m], tmax);
      const float f = __expf(mM[m] - mnew);
      mM[m] = mnew;
      float rs = 0.f;
#pragma unroll
      for (int n = 0; n < 4; ++n)
#pragma unroll
        for (int j = 0; j < 4; ++j) {
          const float e = __expf(sc[m][n][j] - mnew);
          sc[m][n][j] = e; rs += e;
        }
      rs += __shfl_xor(rs, 16);
      rs += __shfl_xor(rs, 32);
      lSum[m] = lSum[m] * f + rs;
#pragma unroll
      for (int n2 = 0; n2 < 8; ++n2) oa[m][n2] *= f;

      unsigned w32[4][2];
#pragma unroll
      for (int n = 0; n < 4; ++n) {
        w32[n][0] = cvt_pk_bf16(sc[m][n][0], sc[m][n][1]);
        w32[n][1] = cvt_pk_bf16(sc[m][n][2], sc[m][n][3]);
      }
      union PF { short8v s; unsigned w[4]; } pfu[2];
#pragma unroll
      for (int kk2 = 0; kk2 < 2; ++kk2) {
#pragma unroll
        for (int hh = 0; hh < 2; ++hh) {
          unsigned u = w32[2 * kk2][hh], v = w32[2 * kk2 + 1][hh];
          asm volatile("v_permlane32_swap_b32 %0, %1" : "+v"(u), "+v"(v));
          asm volatile("v_permlane16_swap_b32 %0, %1" : "+v"(u), "+v"(v));
          pfu[kk2].w[hh] = u;
          pfu[kk2].w[2 + hh] = v;
        }
      }
      pf[m][0] = pfu[0].s;
      pf[m][1] = pfu[1].s;
    }

    if (kt + 1 < nt) asm volatile("s_waitcnt vmcnt(4)" ::: "memory");
    else             asm volatile("s_waitcnt vmcnt(0)" ::: "memory");
    __builtin_amdgcn_s_barrier();

#pragma unroll
    for (int kk2 = 0; kk2 < 2; ++kk2) {
#pragma unroll
      for (int n2 = 0; n2 < 8; ++n2) {
        const int d = n2 * 16 + li;
        const int vbyte = (d * 128 + kk2 * 64 + lg * 16) ^ ((d & 7) << 4);
        const short8v vf = *(const short8v*)((const char*)Vl + vbyte);
        oa[0][n2] = __builtin_amdgcn_mfma_f32_16x16x32_bf16(vf, pf[0][kk2], oa[0][n2], 0, 0, 0);
        oa[1][n2] = __builtin_amdgcn_mfma_f32_16x16x32_bf16(vf, pf[1][kk2], oa[1][n2], 0, 0, 0);
      }
    }
    __builtin_amdgcn_s_barrier();
    if (kt + 1 < nt) STAGE_V(kt + 1);
  }

  {
    char* Ol = (char*)Kl + wave * 8192;
#pragma unroll
    for (int m = 0; m < 2; ++m) {
      const float inv = 1.0f / lSum[m];
      const int q_ = m * 16 + li;
#pragma unroll
      for (int n2 = 0; n2 < 8; ++n2) {
        unsigned lo = cvt_pk_bf16(oa[m][n2][0] * inv, oa[m][n2][1] * inv);
        unsigned hi = cvt_pk_bf16(oa[m][n2][2] * inv, oa[m][n2][3] * inv);
        const int byteo = (q_ * 256 + n2 * 32 + lg * 8) ^ ((q_ & 7) << 4);
        uint2 pr; pr.x = lo; pr.y = hi;
        *(uint2*)(Ol + byteo) = pr;
      }
    }
    asm volatile("s_waitcnt lgkmcnt(0)" ::: "memory");
#pragma unroll
    for (int rr = 0; rr < 4; ++rr) {
      const int r = rr * 8 + (lane >> 3);
      const size_t grow = (size_t)(b * 2048 + qt * 128 + wave * 32 + r) * 2048 + h * 128;
#pragma unroll
      for (int s2 = 0; s2 < 2; ++s2) {
        const int byteo = (r * 256 + (lane & 7) * 32 + s2 * 16) ^ ((r & 7) << 4);
        const u16x8 val = *(const u16x8*)(Ol + byteo);
        *(u16x8*)&attn_out[grow + (lane & 7) * 16 + s2 * 8] = val;
      }
    }
  }
#undef STAGE_K
#undef STAGE_V
}

// ---------------- launch ----------------
extern "C" void kernel_launch(void* const* d_in, const int* in_sizes, int n_in,
                              void* d_out, int out_size, void* d_ws, size_t ws_size,
                              hipStream_t stream) {
  const float* x    = (const float*)d_in[0];   // [2,2048,2048]
  const int*   kpm  = (const int*)d_in[1];     // [2,2048]
  const float* wqkv = (const float*)d_in[2];   // [6144,2048]
  const float* bqkv = (const float*)d_in[3];   // [6144]
  const float* wout = (const float*)d_in[4];   // [2048,2048]
  const float* bout = (const float*)d_in[5];   // [2048]
  float* out = (float*)d_out;

  char* ws = (char*)d_ws;
  u16* xbf   = (u16*)(ws);                    // 16 MiB: x bf16 [4096,2048]
  u16* wqbf  = (u16*)(ws + (16u << 20));      // 24 MiB: Wqkv bf16 [6144,2048]
  u16* wobf  = (u16*)(ws + (40u << 20));      //  8 MiB: out_w bf16 [2048,2048]
  u16* qkvb  = (u16*)(ws + (48u << 20));      // 48 MiB: qkv bf16 [4096,6144]
  u16* vtb   = (u16*)(ws + (96u << 20));      // 16 MiB: V^T bf16 [32,128,2048]
  u16* attnb = (u16*)(ws + (112u << 20));     // 16 MiB: attn bf16 [4096,2048]

  f2bf_kernel<<<1024, 256, 0, stream>>>(x,    xbf,  4096 * 2048 / 4);
  f2bf_kernel<<<1024, 256, 0, stream>>>(wqkv, wqbf, 6144 * 2048 / 4);
  f2bf_kernel<<<1024, 256, 0, stream>>>(wout, wobf, 2048 * 2048 / 4);

  // 128x256 tiles: QKV grid 32*24 = 768 = 3 exact rounds; out-proj 32*8 = 256 = 1 round
  gemm_bt2<1><<<768, 512, 0, stream>>>(xbf, wqbf, bqkv, qkvb, 4096, 6144, 2048);
  transpose_v<<<dim3(32, 32), 256, 0, stream>>>(qkvb, vtb);
  attn_fused<<<dim3(16, 32), 256, 0, stream>>>(qkvb, vtb, kpm, attnb);
  gemm_bt2<0><<<256, 512, 0, stream>>>(attnb, wobf, bout, out, 4096, 2048, 2048);
}